// Round 5
// baseline (252.495 us; speedup 1.0000x reference)
//
#include <hip/hip_runtime.h>
#include <math.h>

// ---- problem constants ----
#define TOK    50176      // 2*8*56*56 tokens
#define CH     128
#define NWIN   128        // B * 64 windows
#define NTOK   392        // 8*7*7 tokens per window
#define NHEADS 4
#define QSCALE 0.17677669529663687f   // 32^-0.5
#define LNEPS  1e-3f

typedef unsigned short u16;
typedef u16   u16x4  __attribute__((ext_vector_type(4)));
typedef u16   u16x8  __attribute__((ext_vector_type(8)));
typedef short s16x8  __attribute__((ext_vector_type(8)));
typedef float f32x4  __attribute__((ext_vector_type(4)));

__device__ __forceinline__ float bf2f(u16 u) {
    return __uint_as_float(((unsigned)u) << 16);
}
__device__ __forceinline__ u16 f2bf(float f) {
    unsigned u = __float_as_uint(f);
    return (u16)((u + 0x7fffu + ((u >> 16) & 1u)) >> 16);
}
__device__ __forceinline__ f32x4 mfma16(s16x8 a, s16x8 b, f32x4 c) {
    return __builtin_amdgcn_mfma_f32_16x16x32_bf16(a, b, c, 0, 0, 0);
}

// token m in window layout -> flat token index in original layout (+3 roll)
__device__ __forceinline__ int src_index(int m) {
    int b = m / NTOK, t = m - b * NTOK;
    int batch = b >> 6, wIdx = b & 63;
    int bh = wIdx >> 3, bw = wIdx & 7;
    int d = t / 49, rem = t - d * 49;
    int h7 = rem / 7, w7 = rem - h7 * 7;
    int h = bh * 7 + h7 + 3; if (h >= 56) h -= 56;
    int w = bw * 7 + w7 + 3; if (w >= 56) w -= 56;
    return ((batch * 8 + d) * 56 + h) * 56 + w;
}

// ---- weight transpose + f32->bf16 convert: dst[n][k] = src[k][n] * sc ----
__global__ __launch_bounds__(256) void convT(
    const float* __restrict__ src, u16* __restrict__ dst,
    int K, int N, int scaleN)
{
    __shared__ float t[32][33];
    int n0 = blockIdx.x * 32, k0 = blockIdx.y * 32;
    int tx = threadIdx.x & 31, ty = threadIdx.x >> 5;   // ty 0..7
    #pragma unroll
    for (int r = 0; r < 4; ++r)
        t[ty + r * 8][tx] = src[(size_t)(k0 + ty + r * 8) * N + n0 + tx];
    __syncthreads();
    #pragma unroll
    for (int r = 0; r < 4; ++r) {
        int n = n0 + ty + r * 8;
        float sc = (n < scaleN) ? QSCALE : 1.f;
        dst[(size_t)n * K + k0 + tx] = f2bf(t[tx][ty + r * 8] * sc);
    }
}

// ---- LayerNorm -> bf16 out ----
template<int MODE>
__global__ __launch_bounds__(128) void ln_kernel(
    const float* __restrict__ xin,
    const float* __restrict__ g, const float* __restrict__ bta,
    u16* __restrict__ out)
{
    int m = blockIdx.x, c = threadIdx.x;
    float v;
    if (MODE == 0) v = xin[(size_t)src_index(m) * CH + c];
    else           v = xin[(size_t)m * CH + c];
    float s1 = v, s2 = v * v;
    #pragma unroll
    for (int o = 32; o; o >>= 1) { s1 += __shfl_xor(s1, o); s2 += __shfl_xor(s2, o); }
    __shared__ float ps[2][2];
    int w = c >> 6;
    if ((c & 63) == 0) { ps[w][0] = s1; ps[w][1] = s2; }
    __syncthreads();
    s1 = ps[0][0] + ps[1][0];
    s2 = ps[0][1] + ps[1][1];
    float mean = s1 * (1.f / CH);
    float var  = s2 * (1.f / CH) - mean * mean;
    float r = rsqrtf(var + LNEPS);
    out[(size_t)m * CH + c] = f2bf((v - mean) * r * g[c] + bta[c]);
}

// ---- MFMA GEMM: C[M][N] = A[M][K]_bf16 * W[N][K]_bf16 + bias, epilogues ----
template<int EPI>
__global__ __launch_bounds__(256) void gemm_mfma(
    const u16* __restrict__ A, const u16* __restrict__ W,
    const float* __restrict__ bias, void* __restrict__ outp,
    int K, int Nn, const float* __restrict__ resid)
{
    __shared__ u16 As[128][32];
    __shared__ u16 Bs[128][32];
    int tid = threadIdx.x, w = tid >> 6, l = tid & 63;
    int c16 = l & 15, g4 = l >> 4;
    int m0 = blockIdx.y * 128, n0 = blockIdx.x * 128;
    int wm = w & 1, wn = w >> 1;

    f32x4 acc[4][4] = {};
    int srow = w * 32 + (l >> 2), scol = (l & 3) * 8;

    for (int k0 = 0; k0 < K; k0 += 32) {
        u16x8 a0 = *(const u16x8*)&A[(size_t)(m0 + srow) * K + k0 + scol];
        u16x8 a1 = *(const u16x8*)&A[(size_t)(m0 + srow + 16) * K + k0 + scol];
        u16x8 b0 = *(const u16x8*)&W[(size_t)(n0 + srow) * K + k0 + scol];
        u16x8 b1 = *(const u16x8*)&W[(size_t)(n0 + srow + 16) * K + k0 + scol];
        *(u16x8*)&As[srow][scol]      = a0;
        *(u16x8*)&As[srow + 16][scol] = a1;
        *(u16x8*)&Bs[srow][scol]      = b0;
        *(u16x8*)&Bs[srow + 16][scol] = b1;
        __syncthreads();

        s16x8 af[4], bf[4];
        #pragma unroll
        for (int mi = 0; mi < 4; ++mi)
            af[mi] = __builtin_bit_cast(s16x8, *(const u16x8*)&As[wm * 64 + mi * 16 + c16][g4 * 8]);
        #pragma unroll
        for (int ni = 0; ni < 4; ++ni)
            bf[ni] = __builtin_bit_cast(s16x8, *(const u16x8*)&Bs[wn * 64 + ni * 16 + c16][g4 * 8]);
        #pragma unroll
        for (int mi = 0; mi < 4; ++mi)
            #pragma unroll
            for (int ni = 0; ni < 4; ++ni)
                acc[mi][ni] = mfma16(af[mi], bf[ni], acc[mi][ni]);
        __syncthreads();
    }

    #pragma unroll
    for (int mi = 0; mi < 4; ++mi) {
        #pragma unroll
        for (int r = 0; r < 4; ++r) {
            int m = m0 + wm * 64 + mi * 16 + g4 * 4 + r;
            int dst = (EPI == 2) ? src_index(m) : m;
            #pragma unroll
            for (int ni = 0; ni < 4; ++ni) {
                int col = n0 + wn * 64 + ni * 16 + c16;
                float v = acc[mi][ni][r];
                if (EPI == 1) {
                    v += bias[col] * (col < 128 ? QSCALE : 1.f);
                    ((u16*)outp)[(size_t)m * Nn + col] = f2bf(v);
                } else if (EPI == 2) {
                    v += bias[col];
                    ((float*)outp)[(size_t)dst * CH + col] = v + resid[(size_t)dst * CH + col];
                } else if (EPI == 3) {
                    v += bias[col];
                    v = 0.5f * v * (1.f + erff(v * 0.70710678118654752f));
                    ((u16*)outp)[(size_t)m * Nn + col] = f2bf(v);
                } else {
                    v += bias[col];
                    ((float*)outp)[(size_t)m * CH + col] = v + resid[(size_t)m * CH + col];
                }
            }
        }
    }
}

// ---- bias+mask table in MFMA C-fragment layout: [hw][t][nt=26][lane][r] bf16 ----
__global__ __launch_bounds__(64) void bias_k(
    const float* __restrict__ rpb, u16* __restrict__ biasT2)
{
    int nt = blockIdx.x;   // 0..25 (col tile; 25 is all -100 pad)
    int t  = blockIdx.y;   // 0..24 (row tile)
    int hw = blockIdx.z;   // head*4 + wt
    int l  = threadIdx.x;  // 0..63
    int head = hw >> 2, wt = hw & 3;
    int bh7 = wt >> 1, bw7 = wt & 1;
    int j = nt * 16 + (l & 15);
    int rb = t * 16 + (l >> 4) * 4;
    u16x4 outv;
    #pragma unroll
    for (int r = 0; r < 4; ++r) {
        int i = rb + r; if (i > NTOK - 1) i = NTOK - 1;
        float v;
        if (j >= NTOK) v = -100.f;
        else {
            int di = i / 49, ri = i - di * 49, hi = ri / 7, wi = ri - hi * 7;
            int dj = j / 49, rj = j - dj * 49, hj = rj / 7, wj = rj - hj * 7;
            int bidx = (di - dj + 7) * 169 + (hi - hj + 6) * 13 + (wi - wj + 6);
            v = rpb[bidx * NHEADS + head];
            int regi = (bh7 ? (hi < 4 ? 1 : 2) : 0) * 3 + (bw7 ? (wi < 4 ? 1 : 2) : 0);
            int regj = (bh7 ? (hj < 4 ? 1 : 2) : 0) * 3 + (bw7 ? (wj < 4 ? 1 : 2) : 0);
            if (regi != regj) v -= 100.f;
        }
        outv[r] = f2bf(v);
    }
    *(u16x4*)&biasT2[((((size_t)hw * 25 + t) * 26 + nt) << 8) + (l << 2)] = outv;
}

// ---- flash-style MFMA attention: one block per (win, head), 4 waves, 2 blk/CU ----
__global__ __launch_bounds__(256, 2) void attn_mfma(
    const u16* __restrict__ Qb, const u16* __restrict__ biasT2,
    u16* __restrict__ O)
{
    __shared__ u16 Kb[416][40];      // 33280 B, rows 400..415 zero
    __shared__ u16 Vt[32][420];      // 26880 B, cols 400..415 zero
    __shared__ u16 Pst[4][16][40];   // 5120 B, per-wave P strip
    // total 65280 B -> 2 blocks/CU

    int bid = blockIdx.x;
    int win = bid >> 2, head = bid & 3;
    int tid = threadIdx.x, w = tid >> 6, l = tid & 63;
    int c16 = l & 15, g4 = l >> 4;

    const size_t qbase = (size_t)win * NTOK * 384;
    for (int e = tid; e < 1600; e += 256) {
        int j = e >> 2, d0 = (e & 3) * 8;
        u16x8 kv = {0, 0, 0, 0, 0, 0, 0, 0};
        u16x8 vv = {0, 0, 0, 0, 0, 0, 0, 0};
        if (j < NTOK) {
            kv = *(const u16x8*)&Qb[qbase + (size_t)j * 384 + 128 + head * 32 + d0];
            vv = *(const u16x8*)&Qb[qbase + (size_t)j * 384 + 256 + head * 32 + d0];
        }
        *(u16x8*)&Kb[j][d0] = kv;
        #pragma unroll
        for (int i = 0; i < 8; ++i) Vt[d0 + i][j] = vv[i];
    }
    for (int e = tid; e < 16 * 32; e += 256)
        Kb[400 + (e >> 5)][e & 31] = 0;
    for (int e = tid; e < 32 * 16; e += 256)
        Vt[e >> 4][400 + (e & 15)] = 0;
    __syncthreads();

    int wIdx = win & 63;
    int wt = (((wIdx >> 3) == 7) ? 2 : 0) + (((wIdx & 7) == 7) ? 1 : 0);
    const u16* bt = biasT2 + (((size_t)(head * 4 + wt) * 25 * 26) << 8) + (l << 2);
    u16 (*myP)[40] = Pst[w];

    for (int t = w; t < 25; t += 4) {
        int row0 = t * 16;
        int qr = row0 + c16; if (qr > NTOK - 1) qr = NTOK - 1;
        s16x8 afrag = __builtin_bit_cast(s16x8,
            *(const u16x8*)&Qb[qbase + (size_t)qr * 384 + head * 32 + g4 * 8]);
        const u16* btt = bt + (((size_t)t * 26) << 8);

        float m4[4] = {-1e30f, -1e30f, -1e30f, -1e30f};
        float l4[4] = {0.f, 0.f, 0.f, 0.f};
        f32x4 oacc[2] = {{0.f,0.f,0.f,0.f},{0.f,0.f,0.f,0.f}};

        for (int jb = 0; jb < 13; ++jb) {
            // QK^T for this 32-k strip (2 nt tiles)
            f32x4 s[2];
            #pragma unroll
            for (int kk = 0; kk < 2; ++kk) {
                s16x8 bfrag = __builtin_bit_cast(s16x8,
                    *(const u16x8*)&Kb[(jb * 2 + kk) * 16 + c16][g4 * 8]);
                f32x4 zz = {0.f, 0.f, 0.f, 0.f};
                s[kk] = mfma16(afrag, bfrag, zz);
            }
            // bias + mask add
            #pragma unroll
            for (int kk = 0; kk < 2; ++kk) {
                u16x4 b4 = *(const u16x4*)(btt + (((size_t)(jb * 2 + kk)) << 8));
                #pragma unroll
                for (int r = 0; r < 4; ++r) s[kk][r] += bf2f(b4[r]);
            }
            // strip row-max
            float ms[4];
            #pragma unroll
            for (int r = 0; r < 4; ++r) {
                ms[r] = fmaxf(s[0][r], s[1][r]);
                #pragma unroll
                for (int o = 1; o <= 8; o <<= 1)
                    ms[r] = fmaxf(ms[r], __shfl_xor(ms[r], o));
            }
            // online rescale
            float sc[4];
            #pragma unroll
            for (int r = 0; r < 4; ++r) {
                float mn = fmaxf(m4[r], ms[r]);
                sc[r] = exp2f((m4[r] - mn) * 1.44269504f);
                m4[r] = mn;
            }
            // exp, strip sum, P-strip write
            float ssum[4] = {0.f, 0.f, 0.f, 0.f};
            #pragma unroll
            for (int kk = 0; kk < 2; ++kk)
                #pragma unroll
                for (int r = 0; r < 4; ++r) {
                    float p = exp2f((s[kk][r] - m4[r]) * 1.44269504f);
                    ssum[r] += p;
                    myP[g4 * 4 + r][kk * 16 + c16] = f2bf(p);
                }
            #pragma unroll
            for (int r = 0; r < 4; ++r) {
                #pragma unroll
                for (int o = 1; o <= 8; o <<= 1)
                    ssum[r] += __shfl_xor(ssum[r], o);
                l4[r] = l4[r] * sc[r] + ssum[r];
            }
            #pragma unroll
            for (int nd = 0; nd < 2; ++nd)
                #pragma unroll
                for (int r = 0; r < 4; ++r) oacc[nd][r] *= sc[r];
            // PV for this strip
            s16x8 pa = __builtin_bit_cast(s16x8, *(const u16x8*)&myP[c16][g4 * 8]);
            #pragma unroll
            for (int nd = 0; nd < 2; ++nd) {
                s16x8 vb = __builtin_bit_cast(s16x8,
                    *(const u16x8*)&Vt[nd * 16 + c16][jb * 32 + g4 * 8]);
                oacc[nd] = mfma16(pa, vb, oacc[nd]);
            }
        }

        #pragma unroll
        for (int nd = 0; nd < 2; ++nd)
            #pragma unroll
            for (int r = 0; r < 4; ++r) {
                int qrow = row0 + g4 * 4 + r;
                if (qrow < NTOK)
                    O[((size_t)(win * NTOK + qrow)) * CH + head * 32 + nd * 16 + c16]
                        = f2bf(oacc[nd][r] / l4[r]);
            }
    }
}

extern "C" void kernel_launch(void* const* d_in, const int* in_sizes, int n_in,
                              void* d_out, int out_size, void* d_ws, size_t ws_size,
                              hipStream_t stream) {
    const float* x      = (const float*)d_in[0];
    const float* n1g    = (const float*)d_in[1];
    const float* n1b    = (const float*)d_in[2];
    const float* qkv_w  = (const float*)d_in[3];
    const float* qkv_b  = (const float*)d_in[4];
    const float* proj_w = (const float*)d_in[5];
    const float* proj_b = (const float*)d_in[6];
    const float* rpb    = (const float*)d_in[7];
    const float* n2g    = (const float*)d_in[8];
    const float* n2b    = (const float*)d_in[9];
    const float* fc1_w  = (const float*)d_in[10];
    const float* fc1_b  = (const float*)d_in[11];
    const float* fc2_w  = (const float*)d_in[12];
    const float* fc2_b  = (const float*)d_in[13];
    float* out = (float*)d_out;

    char* ws = (char*)d_ws;
    size_t off = 0;
    u16* A_bf  = (u16*)(ws + off);  off += (size_t)TOK * 128 * 2;
    u16* Qb_bf = (u16*)(ws + off);  off += (size_t)TOK * 384 * 2;
    u16* O_bf  = (u16*)(ws + off);  off += (size_t)TOK * 128 * 2;
    float* R   = (float*)(ws + off); off += (size_t)TOK * 128 * 4;
    u16* biasT2 = (u16*)(ws + off); off += (size_t)16 * 25 * 26 * 256 * 2;
    u16* qkvT  = (u16*)(ws + off);  off += 384 * 128 * 2;
    u16* projT = (u16*)(ws + off);  off += 128 * 128 * 2;
    u16* fc1T  = (u16*)(ws + off);  off += 512 * 128 * 2;
    u16* fc2T  = (u16*)(ws + off);  off += 128 * 512 * 2;
    u16* H_bf  = Qb_bf;  // overlays Qb+O exactly; both dead by fc1

    // 0. weight transposes (+bf16), QSCALE folded into Wq
    hipLaunchKernelGGL(convT, dim3(384/32, 128/32), dim3(256), 0, stream, qkv_w,  qkvT, 128, 384, 128);
    hipLaunchKernelGGL(convT, dim3(128/32, 128/32), dim3(256), 0, stream, proj_w, projT, 128, 128, 0);
    hipLaunchKernelGGL(convT, dim3(512/32, 128/32), dim3(256), 0, stream, fc1_w,  fc1T, 128, 512, 0);
    hipLaunchKernelGGL(convT, dim3(128/32, 512/32), dim3(256), 0, stream, fc2_w,  fc2T, 512, 128, 0);
    // 0b. bias+mask table in fragment layout (26 nt tiles)
    hipLaunchKernelGGL(bias_k, dim3(26, 25, 16), dim3(64), 0, stream, rpb, biasT2);
    // 1. LN1 + shift + window_partition -> bf16
    hipLaunchKernelGGL((ln_kernel<0>), dim3(TOK), dim3(128), 0, stream, x, n1g, n1b, A_bf);
    // 2. qkv GEMM -> bf16
    hipLaunchKernelGGL((gemm_mfma<1>), dim3(3, TOK/128), dim3(256), 0, stream,
                       A_bf, qkvT, qkv_b, Qb_bf, 128, 384, nullptr);
    // 3. flash MFMA windowed attention -> bf16
    hipLaunchKernelGGL(attn_mfma, dim3(NWIN * NHEADS), dim3(256), 0, stream,
                       Qb_bf, biasT2, O_bf);
    // 4. proj GEMM + unshift + residual -> f32 R
    hipLaunchKernelGGL((gemm_mfma<2>), dim3(1, TOK/128), dim3(256), 0, stream,
                       O_bf, projT, proj_b, R, 128, 128, x);
    // 5. LN2 -> bf16
    hipLaunchKernelGGL((ln_kernel<1>), dim3(TOK), dim3(128), 0, stream, R, n2g, n2b, A_bf);
    // 6. fc1 + GELU -> bf16
    hipLaunchKernelGGL((gemm_mfma<3>), dim3(4, TOK/128), dim3(256), 0, stream,
                       A_bf, fc1T, fc1_b, H_bf, 128, 512, nullptr);
    // 7. fc2 + residual -> f32 out
    hipLaunchKernelGGL((gemm_mfma<4>), dim3(1, TOK/128), dim3(256), 0, stream,
                       H_bf, fc2T, fc2_b, out, 512, 128, R);
}

// Round 6
// 208.985 us; speedup vs baseline: 1.2082x; 1.2082x over previous
//
#include <hip/hip_runtime.h>
#include <math.h>

// ---- problem constants ----
#define TOK    50176      // 2*8*56*56 tokens
#define CH     128
#define NWIN   128        // B * 64 windows
#define NTOK   392        // 8*7*7 tokens per window
#define NHEADS 4
#define QSCALE 0.17677669529663687f   // 32^-0.5
#define LNEPS  1e-3f

typedef unsigned short u16;
typedef u16   u16x4  __attribute__((ext_vector_type(4)));
typedef u16   u16x8  __attribute__((ext_vector_type(8)));
typedef short s16x8  __attribute__((ext_vector_type(8)));
typedef float f32x4  __attribute__((ext_vector_type(4)));

__device__ __forceinline__ float bf2f(u16 u) {
    return __uint_as_float(((unsigned)u) << 16);
}
__device__ __forceinline__ u16 f2bf(float f) {
    unsigned u = __float_as_uint(f);
    return (u16)((u + 0x7fffu + ((u >> 16) & 1u)) >> 16);
}
__device__ __forceinline__ f32x4 mfma16(s16x8 a, s16x8 b, f32x4 c) {
    return __builtin_amdgcn_mfma_f32_16x16x32_bf16(a, b, c, 0, 0, 0);
}

// token m in window layout -> flat token index in original layout (+3 roll)
__device__ __forceinline__ int src_index(int m) {
    int b = m / NTOK, t = m - b * NTOK;
    int batch = b >> 6, wIdx = b & 63;
    int bh = wIdx >> 3, bw = wIdx & 7;
    int d = t / 49, rem = t - d * 49;
    int h7 = rem / 7, w7 = rem - h7 * 7;
    int h = bh * 7 + h7 + 3; if (h >= 56) h -= 56;
    int w = bw * 7 + w7 + 3; if (w >= 56) w -= 56;
    return ((batch * 8 + d) * 56 + h) * 56 + w;
}

// ---- weight transpose + f32->bf16 convert: dst[n][k] = src[k][n] * sc ----
__global__ __launch_bounds__(256) void convT(
    const float* __restrict__ src, u16* __restrict__ dst,
    int K, int N, int scaleN)
{
    __shared__ float t[32][33];
    int n0 = blockIdx.x * 32, k0 = blockIdx.y * 32;
    int tx = threadIdx.x & 31, ty = threadIdx.x >> 5;   // ty 0..7
    #pragma unroll
    for (int r = 0; r < 4; ++r)
        t[ty + r * 8][tx] = src[(size_t)(k0 + ty + r * 8) * N + n0 + tx];
    __syncthreads();
    #pragma unroll
    for (int r = 0; r < 4; ++r) {
        int n = n0 + ty + r * 8;
        float sc = (n < scaleN) ? QSCALE : 1.f;
        dst[(size_t)n * K + k0 + tx] = f2bf(t[tx][ty + r * 8] * sc);
    }
}

// ---- LayerNorm -> bf16 out ----
template<int MODE>
__global__ __launch_bounds__(128) void ln_kernel(
    const float* __restrict__ xin,
    const float* __restrict__ g, const float* __restrict__ bta,
    u16* __restrict__ out)
{
    int m = blockIdx.x, c = threadIdx.x;
    float v;
    if (MODE == 0) v = xin[(size_t)src_index(m) * CH + c];
    else           v = xin[(size_t)m * CH + c];
    float s1 = v, s2 = v * v;
    #pragma unroll
    for (int o = 32; o; o >>= 1) { s1 += __shfl_xor(s1, o); s2 += __shfl_xor(s2, o); }
    __shared__ float ps[2][2];
    int w = c >> 6;
    if ((c & 63) == 0) { ps[w][0] = s1; ps[w][1] = s2; }
    __syncthreads();
    s1 = ps[0][0] + ps[1][0];
    s2 = ps[0][1] + ps[1][1];
    float mean = s1 * (1.f / CH);
    float var  = s2 * (1.f / CH) - mean * mean;
    float r = rsqrtf(var + LNEPS);
    out[(size_t)m * CH + c] = f2bf((v - mean) * r * g[c] + bta[c]);
}

// ---- MFMA GEMM: C[M][N] = A[M][K]_bf16 * W[N][K]_bf16 + bias, epilogues ----
template<int EPI>
__global__ __launch_bounds__(256) void gemm_mfma(
    const u16* __restrict__ A, const u16* __restrict__ W,
    const float* __restrict__ bias, void* __restrict__ outp,
    int K, int Nn, const float* __restrict__ resid)
{
    __shared__ u16 As[128][32];
    __shared__ u16 Bs[128][32];
    int tid = threadIdx.x, w = tid >> 6, l = tid & 63;
    int c16 = l & 15, g4 = l >> 4;
    int m0 = blockIdx.y * 128, n0 = blockIdx.x * 128;
    int wm = w & 1, wn = w >> 1;

    f32x4 acc[4][4] = {};
    int srow = w * 32 + (l >> 2), scol = (l & 3) * 8;

    for (int k0 = 0; k0 < K; k0 += 32) {
        u16x8 a0 = *(const u16x8*)&A[(size_t)(m0 + srow) * K + k0 + scol];
        u16x8 a1 = *(const u16x8*)&A[(size_t)(m0 + srow + 16) * K + k0 + scol];
        u16x8 b0 = *(const u16x8*)&W[(size_t)(n0 + srow) * K + k0 + scol];
        u16x8 b1 = *(const u16x8*)&W[(size_t)(n0 + srow + 16) * K + k0 + scol];
        *(u16x8*)&As[srow][scol]      = a0;
        *(u16x8*)&As[srow + 16][scol] = a1;
        *(u16x8*)&Bs[srow][scol]      = b0;
        *(u16x8*)&Bs[srow + 16][scol] = b1;
        __syncthreads();

        s16x8 af[4], bf[4];
        #pragma unroll
        for (int mi = 0; mi < 4; ++mi)
            af[mi] = __builtin_bit_cast(s16x8, *(const u16x8*)&As[wm * 64 + mi * 16 + c16][g4 * 8]);
        #pragma unroll
        for (int ni = 0; ni < 4; ++ni)
            bf[ni] = __builtin_bit_cast(s16x8, *(const u16x8*)&Bs[wn * 64 + ni * 16 + c16][g4 * 8]);
        #pragma unroll
        for (int mi = 0; mi < 4; ++mi)
            #pragma unroll
            for (int ni = 0; ni < 4; ++ni)
                acc[mi][ni] = mfma16(af[mi], bf[ni], acc[mi][ni]);
        __syncthreads();
    }

    #pragma unroll
    for (int mi = 0; mi < 4; ++mi) {
        #pragma unroll
        for (int r = 0; r < 4; ++r) {
            int m = m0 + wm * 64 + mi * 16 + g4 * 4 + r;
            int dst = (EPI == 2) ? src_index(m) : m;
            #pragma unroll
            for (int ni = 0; ni < 4; ++ni) {
                int col = n0 + wn * 64 + ni * 16 + c16;
                float v = acc[mi][ni][r];
                if (EPI == 1) {
                    v += bias[col] * (col < 128 ? QSCALE : 1.f);
                    ((u16*)outp)[(size_t)m * Nn + col] = f2bf(v);
                } else if (EPI == 2) {
                    v += bias[col];
                    ((float*)outp)[(size_t)dst * CH + col] = v + resid[(size_t)dst * CH + col];
                } else if (EPI == 3) {
                    v += bias[col];
                    v = 0.5f * v * (1.f + erff(v * 0.70710678118654752f));
                    ((u16*)outp)[(size_t)m * Nn + col] = f2bf(v);
                } else {
                    v += bias[col];
                    ((float*)outp)[(size_t)m * CH + col] = v + resid[(size_t)m * CH + col];
                }
            }
        }
    }
}

// ---- bias+mask table, f32, MFMA C-fragment layout: [hw][t][nt=26][lane][r] ----
__global__ __launch_bounds__(64) void bias_k(
    const float* __restrict__ rpb, float* __restrict__ biasT2)
{
    int nt = blockIdx.x;   // 0..25 (col tile; 25 is all -100 pad)
    int t  = blockIdx.y;   // 0..24 (row tile)
    int hw = blockIdx.z;   // head*4 + wt
    int l  = threadIdx.x;  // 0..63
    int head = hw >> 2, wt = hw & 3;
    int bh7 = wt >> 1, bw7 = wt & 1;
    int j = nt * 16 + (l & 15);
    int rb = t * 16 + (l >> 4) * 4;
    f32x4 outv;
    #pragma unroll
    for (int r = 0; r < 4; ++r) {
        int i = rb + r; if (i > NTOK - 1) i = NTOK - 1;
        float v;
        if (j >= NTOK) v = -100.f;
        else {
            int di = i / 49, ri = i - di * 49, hi = ri / 7, wi = ri - hi * 7;
            int dj = j / 49, rj = j - dj * 49, hj = rj / 7, wj = rj - hj * 7;
            int bidx = (di - dj + 7) * 169 + (hi - hj + 6) * 13 + (wi - wj + 6);
            v = rpb[bidx * NHEADS + head];
            int regi = (bh7 ? (hi < 4 ? 1 : 2) : 0) * 3 + (bw7 ? (wi < 4 ? 1 : 2) : 0);
            int regj = (bh7 ? (hj < 4 ? 1 : 2) : 0) * 3 + (bw7 ? (wj < 4 ? 1 : 2) : 0);
            if (regi != regj) v -= 100.f;
        }
        outv[r] = v;
    }
    *(f32x4*)&biasT2[((((size_t)hw * 25 + t) * 26 + nt) << 8) + (l << 2)] = outv;
}

// ---- flash-strip MFMA attention, no-max softmax, bias in MFMA C-operand ----
// one block per (win, head), 4 waves, 2 blk/CU
__global__ __launch_bounds__(256, 2) void attn_mfma(
    const u16* __restrict__ Qb, const float* __restrict__ biasT2,
    u16* __restrict__ O)
{
    __shared__ u16 Kb[416][40];      // 33280 B, rows 400..415 zero
    __shared__ u16 Vt[32][420];      // 26880 B, cols 400..415 zero
    __shared__ u16 Pst[4][16][40];   // 5120 B, per-wave P strip
    // total 65280 B -> 2 blocks/CU

    int bid = blockIdx.x;
    int win = bid >> 2, head = bid & 3;
    int tid = threadIdx.x, w = tid >> 6, l = tid & 63;
    int c16 = l & 15, g4 = l >> 4;

    const size_t qbase = (size_t)win * NTOK * 384;
    for (int e = tid; e < 1600; e += 256) {
        int j = e >> 2, d0 = (e & 3) * 8;
        u16x8 kv = {0, 0, 0, 0, 0, 0, 0, 0};
        u16x8 vv = {0, 0, 0, 0, 0, 0, 0, 0};
        if (j < NTOK) {
            kv = *(const u16x8*)&Qb[qbase + (size_t)j * 384 + 128 + head * 32 + d0];
            vv = *(const u16x8*)&Qb[qbase + (size_t)j * 384 + 256 + head * 32 + d0];
        }
        *(u16x8*)&Kb[j][d0] = kv;
        #pragma unroll
        for (int i = 0; i < 8; ++i) Vt[d0 + i][j] = vv[i];
    }
    for (int e = tid; e < 16 * 32; e += 256)
        Kb[400 + (e >> 5)][e & 31] = 0;
    for (int e = tid; e < 32 * 16; e += 256)
        Vt[e >> 4][400 + (e & 15)] = 0;
    __syncthreads();

    int wIdx = win & 63;
    int wt = (((wIdx >> 3) == 7) ? 2 : 0) + (((wIdx & 7) == 7) ? 1 : 0);
    const float* bt = biasT2 + (((size_t)(head * 4 + wt) * 25 * 26) << 8) + (l << 2);
    u16 (*myP)[40] = Pst[w];

    for (int t = w; t < 25; t += 4) {
        int row0 = t * 16;
        int qr = row0 + c16; if (qr > NTOK - 1) qr = NTOK - 1;
        s16x8 afrag = __builtin_bit_cast(s16x8,
            *(const u16x8*)&Qb[qbase + (size_t)qr * 384 + head * 32 + g4 * 8]);
        const float* btt = bt + (((size_t)t * 26) << 8);

        float l4[4] = {0.f, 0.f, 0.f, 0.f};
        f32x4 oacc[2] = {{0.f,0.f,0.f,0.f},{0.f,0.f,0.f,0.f}};

        for (int jb = 0; jb < 13; ++jb) {
            // QK^T for this 32-k strip; bias+mask preloaded as the accumulator
            f32x4 s[2];
            #pragma unroll
            for (int kk = 0; kk < 2; ++kk) {
                f32x4 cb = *(const f32x4*)(btt + (((size_t)(jb * 2 + kk)) << 8));
                s16x8 bfrag = __builtin_bit_cast(s16x8,
                    *(const u16x8*)&Kb[(jb * 2 + kk) * 16 + c16][g4 * 8]);
                s[kk] = mfma16(afrag, bfrag, cb);
            }
            // exp (no max subtraction: scores are small; masked -> underflow to 0)
            #pragma unroll
            for (int kk = 0; kk < 2; ++kk)
                #pragma unroll
                for (int r = 0; r < 4; ++r) {
                    float p = exp2f(s[kk][r] * 1.44269504f);
                    l4[r] += p;
                    myP[g4 * 4 + r][kk * 16 + c16] = f2bf(p);
                }
            // PV for this strip
            s16x8 pa = __builtin_bit_cast(s16x8, *(const u16x8*)&myP[c16][g4 * 8]);
            #pragma unroll
            for (int nd = 0; nd < 2; ++nd) {
                s16x8 vb = __builtin_bit_cast(s16x8,
                    *(const u16x8*)&Vt[nd * 16 + c16][jb * 32 + g4 * 8]);
                oacc[nd] = mfma16(pa, vb, oacc[nd]);
            }
        }

        // row sum: reduce partial sums across the 16 lanes of each row group
        #pragma unroll
        for (int r = 0; r < 4; ++r) {
            #pragma unroll
            for (int o = 1; o <= 8; o <<= 1)
                l4[r] += __shfl_xor(l4[r], o);
            l4[r] = 1.f / l4[r];
        }

        #pragma unroll
        for (int nd = 0; nd < 2; ++nd)
            #pragma unroll
            for (int r = 0; r < 4; ++r) {
                int qrow = row0 + g4 * 4 + r;
                if (qrow < NTOK)
                    O[((size_t)(win * NTOK + qrow)) * CH + head * 32 + nd * 16 + c16]
                        = f2bf(oacc[nd][r] * l4[r]);
            }
    }
}

extern "C" void kernel_launch(void* const* d_in, const int* in_sizes, int n_in,
                              void* d_out, int out_size, void* d_ws, size_t ws_size,
                              hipStream_t stream) {
    const float* x      = (const float*)d_in[0];
    const float* n1g    = (const float*)d_in[1];
    const float* n1b    = (const float*)d_in[2];
    const float* qkv_w  = (const float*)d_in[3];
    const float* qkv_b  = (const float*)d_in[4];
    const float* proj_w = (const float*)d_in[5];
    const float* proj_b = (const float*)d_in[6];
    const float* rpb    = (const float*)d_in[7];
    const float* n2g    = (const float*)d_in[8];
    const float* n2b    = (const float*)d_in[9];
    const float* fc1_w  = (const float*)d_in[10];
    const float* fc1_b  = (const float*)d_in[11];
    const float* fc2_w  = (const float*)d_in[12];
    const float* fc2_b  = (const float*)d_in[13];
    float* out = (float*)d_out;

    char* ws = (char*)d_ws;
    size_t off = 0;
    u16* A_bf  = (u16*)(ws + off);  off += (size_t)TOK * 128 * 2;   // 12.85 MB
    u16* Qb_bf = (u16*)(ws + off);  off += (size_t)TOK * 384 * 2;
    u16* O_bf  = (u16*)(ws + off);  off += (size_t)TOK * 128 * 2;
    float* R   = (float*)(ws + off); off += (size_t)TOK * 128 * 4;
    u16* qkvT  = (u16*)(ws + off);  off += 384 * 128 * 2;
    u16* projT = (u16*)(ws + off);  off += 128 * 128 * 2;
    u16* fc1T  = (u16*)(ws + off);  off += 512 * 128 * 2;
    u16* fc2T  = (u16*)(ws + off);  off += 128 * 512 * 2;
    u16* H_bf  = Qb_bf;             // overlays Qb+O exactly; both dead by fc1
    float* biasT2 = (float*)A_bf;   // 10.65 MB overlay; A_bf dead after qkv GEMM,
                                    // rewritten by LN2 after attn is done

    // 0. weight transposes (+bf16), QSCALE folded into Wq
    hipLaunchKernelGGL(convT, dim3(384/32, 128/32), dim3(256), 0, stream, qkv_w,  qkvT, 128, 384, 128);
    hipLaunchKernelGGL(convT, dim3(128/32, 128/32), dim3(256), 0, stream, proj_w, projT, 128, 128, 0);
    hipLaunchKernelGGL(convT, dim3(512/32, 128/32), dim3(256), 0, stream, fc1_w,  fc1T, 128, 512, 0);
    hipLaunchKernelGGL(convT, dim3(128/32, 512/32), dim3(256), 0, stream, fc2_w,  fc2T, 512, 128, 0);
    // 1. LN1 + shift + window_partition -> bf16
    hipLaunchKernelGGL((ln_kernel<0>), dim3(TOK), dim3(128), 0, stream, x, n1g, n1b, A_bf);
    // 2. qkv GEMM -> bf16
    hipLaunchKernelGGL((gemm_mfma<1>), dim3(3, TOK/128), dim3(256), 0, stream,
                       A_bf, qkvT, qkv_b, Qb_bf, 128, 384, nullptr);
    // 2b. bias+mask table (A_bf is dead now; overlay)
    hipLaunchKernelGGL(bias_k, dim3(26, 25, 16), dim3(64), 0, stream, rpb, biasT2);
    // 3. flash MFMA windowed attention -> bf16
    hipLaunchKernelGGL(attn_mfma, dim3(NWIN * NHEADS), dim3(256), 0, stream,
                       Qb_bf, biasT2, O_bf);
    // 4. proj GEMM + unshift + residual -> f32 R
    hipLaunchKernelGGL((gemm_mfma<2>), dim3(1, TOK/128), dim3(256), 0, stream,
                       O_bf, projT, proj_b, R, 128, 128, x);
    // 5. LN2 -> bf16
    hipLaunchKernelGGL((ln_kernel<1>), dim3(TOK), dim3(128), 0, stream, R, n2g, n2b, A_bf);
    // 6. fc1 + GELU -> bf16
    hipLaunchKernelGGL((gemm_mfma<3>), dim3(4, TOK/128), dim3(256), 0, stream,
                       A_bf, fc1T, fc1_b, H_bf, 128, 512, nullptr);
    // 7. fc2 + residual -> f32 out
    hipLaunchKernelGGL((gemm_mfma<4>), dim3(1, TOK/128), dim3(256), 0, stream,
                       H_bf, fc2T, fc2_b, out, 512, 128, R);
}

// Round 7
// 203.665 us; speedup vs baseline: 1.2398x; 1.0261x over previous
//
#include <hip/hip_runtime.h>
#include <math.h>

// ---- problem constants ----
#define TOK    50176      // 2*8*56*56 tokens
#define CH     128
#define NWIN   128        // B * 64 windows
#define NTOK   392        // 8*7*7 tokens per window
#define NHEADS 4
#define QSCALE 0.17677669529663687f   // 32^-0.5
#define LNEPS  1e-3f

typedef unsigned short u16;
typedef u16   u16x4  __attribute__((ext_vector_type(4)));
typedef u16   u16x8  __attribute__((ext_vector_type(8)));
typedef short s16x8  __attribute__((ext_vector_type(8)));
typedef float f32x4  __attribute__((ext_vector_type(4)));

__device__ __forceinline__ float bf2f(u16 u) {
    return __uint_as_float(((unsigned)u) << 16);
}
__device__ __forceinline__ u16 f2bf(float f) {
    unsigned u = __float_as_uint(f);
    return (u16)((u + 0x7fffu + ((u >> 16) & 1u)) >> 16);
}
__device__ __forceinline__ f32x4 mfma16(s16x8 a, s16x8 b, f32x4 c) {
    return __builtin_amdgcn_mfma_f32_16x16x32_bf16(a, b, c, 0, 0, 0);
}

// token m in window layout -> flat token index in original layout (+3 roll)
__device__ __forceinline__ int src_index(int m) {
    int b = m / NTOK, t = m - b * NTOK;
    int batch = b >> 6, wIdx = b & 63;
    int bh = wIdx >> 3, bw = wIdx & 7;
    int d = t / 49, rem = t - d * 49;
    int h7 = rem / 7, w7 = rem - h7 * 7;
    int h = bh * 7 + h7 + 3; if (h >= 56) h -= 56;
    int w = bw * 7 + w7 + 3; if (w >= 56) w -= 56;
    return ((batch * 8 + d) * 56 + h) * 56 + w;
}

// ---- weight transpose + f32->bf16 convert: dst[n][k] = src[k][n] * sc ----
__global__ __launch_bounds__(256) void convT(
    const float* __restrict__ src, u16* __restrict__ dst,
    int K, int N, int scaleN)
{
    __shared__ float t[32][33];
    int n0 = blockIdx.x * 32, k0 = blockIdx.y * 32;
    int tx = threadIdx.x & 31, ty = threadIdx.x >> 5;   // ty 0..7
    #pragma unroll
    for (int r = 0; r < 4; ++r)
        t[ty + r * 8][tx] = src[(size_t)(k0 + ty + r * 8) * N + n0 + tx];
    __syncthreads();
    #pragma unroll
    for (int r = 0; r < 4; ++r) {
        int n = n0 + ty + r * 8;
        float sc = (n < scaleN) ? QSCALE : 1.f;
        dst[(size_t)n * K + k0 + tx] = f2bf(t[tx][ty + r * 8] * sc);
    }
}

// ---- LN1: gather f32 x via src_index, LN, -> bf16 window layout ----
__global__ __launch_bounds__(128) void ln_kernel(
    const float* __restrict__ xin,
    const float* __restrict__ g, const float* __restrict__ bta,
    u16* __restrict__ out)
{
    int m = blockIdx.x, c = threadIdx.x;
    float v = xin[(size_t)src_index(m) * CH + c];
    float s1 = v, s2 = v * v;
    #pragma unroll
    for (int o = 32; o; o >>= 1) { s1 += __shfl_xor(s1, o); s2 += __shfl_xor(s2, o); }
    __shared__ float ps[2][2];
    int w = c >> 6;
    if ((c & 63) == 0) { ps[w][0] = s1; ps[w][1] = s2; }
    __syncthreads();
    s1 = ps[0][0] + ps[1][0];
    s2 = ps[0][1] + ps[1][1];
    float mean = s1 * (1.f / CH);
    float var  = s2 * (1.f / CH) - mean * mean;
    float r = rsqrtf(var + LNEPS);
    out[(size_t)m * CH + c] = f2bf((v - mean) * r * g[c] + bta[c]);
}

// ---- MFMA GEMM, BK=128 single-stage + reg prefetch across 128-chunks ----
// C[M][N] = A[M][K]_bf16 * W[N][K]_bf16 + bias
// EPI 1: qkv -> bf16 (bias QSCALE'd for n<128)
// EPI 2: proj + residual scatter -> f32 R, FUSED LN2 -> bf16 ln_out
// EPI 3: gelu -> bf16
// EPI 4: fc2 + resid f32 -> f32 out
template<int EPI, int KTOT>
__global__ __launch_bounds__(256, 2) void gemm_mfma(
    const u16* __restrict__ A, const u16* __restrict__ W,
    const float* __restrict__ bias, void* __restrict__ outp,
    int Nn, const float* __restrict__ resid,
    const float* __restrict__ lng, const float* __restrict__ lnb,
    u16* __restrict__ ln_out)
{
    __shared__ u16 As[4][128][32];   // 32 KB  (chunk-major: [kc][row][k32])
    __shared__ u16 Bs[4][128][32];   // 32 KB
    __shared__ float lnred[2][2][64][2]; // [wn][wm][rl][sum,sq]  2 KB

    int tid = threadIdx.x, w = tid >> 6, l = tid & 63;
    int c16 = l & 15, g4 = l >> 4;
    int m0 = blockIdx.y * 128, n0 = blockIdx.x * 128;
    int wm = w & 1, wn = w >> 1;
    const int NCH = KTOT / 128;

    f32x4 acc[4][4] = {};
    u16x8 va[8], vb[8];

    #pragma unroll
    for (int p = 0; p < 8; ++p) {
        int e = tid + p * 256, row = e >> 4, c8 = e & 15;
        va[p] = *(const u16x8*)&A[(size_t)(m0 + row) * KTOT + c8 * 8];
        vb[p] = *(const u16x8*)&W[(size_t)(n0 + row) * KTOT + c8 * 8];
    }
    for (int ch = 0; ch < NCH; ++ch) {
        #pragma unroll
        for (int p = 0; p < 8; ++p) {
            int e = tid + p * 256, row = e >> 4, c8 = e & 15;
            *(u16x8*)&As[c8 >> 2][row][(c8 & 3) * 8] = va[p];
            *(u16x8*)&Bs[c8 >> 2][row][(c8 & 3) * 8] = vb[p];
        }
        __syncthreads();
        if (ch + 1 < NCH) {
            #pragma unroll
            for (int p = 0; p < 8; ++p) {
                int e = tid + p * 256, row = e >> 4, c8 = e & 15;
                va[p] = *(const u16x8*)&A[(size_t)(m0 + row) * KTOT + (ch + 1) * 128 + c8 * 8];
                vb[p] = *(const u16x8*)&W[(size_t)(n0 + row) * KTOT + (ch + 1) * 128 + c8 * 8];
            }
        }
        #pragma unroll
        for (int kc = 0; kc < 4; ++kc) {
            s16x8 af[4], bf[4];
            #pragma unroll
            for (int mi = 0; mi < 4; ++mi)
                af[mi] = __builtin_bit_cast(s16x8,
                    *(const u16x8*)&As[kc][wm * 64 + mi * 16 + c16][g4 * 8]);
            #pragma unroll
            for (int ni = 0; ni < 4; ++ni)
                bf[ni] = __builtin_bit_cast(s16x8,
                    *(const u16x8*)&Bs[kc][wn * 64 + ni * 16 + c16][g4 * 8]);
            #pragma unroll
            for (int mi = 0; mi < 4; ++mi)
                #pragma unroll
                for (int ni = 0; ni < 4; ++ni)
                    acc[mi][ni] = mfma16(af[mi], bf[ni], acc[mi][ni]);
        }
        if (ch + 1 < NCH) __syncthreads();
    }

    if (EPI == 2) {
        // v = acc + bias + resid (overwrite acc); per-row partial sums for LN
        float psum[4][4], psq[4][4];
        #pragma unroll
        for (int mi = 0; mi < 4; ++mi)
            #pragma unroll
            for (int r = 0; r < 4; ++r) {
                int m = m0 + wm * 64 + mi * 16 + g4 * 4 + r;
                int dst = src_index(m);
                float s = 0.f, q = 0.f;
                #pragma unroll
                for (int ni = 0; ni < 4; ++ni) {
                    int col = wn * 64 + ni * 16 + c16;
                    float v = acc[mi][ni][r] + bias[col] + resid[(size_t)dst * CH + col];
                    acc[mi][ni][r] = v;
                    s += v; q += v * v;
                }
                psum[mi][r] = s; psq[mi][r] = q;
            }
        #pragma unroll
        for (int o = 1; o <= 8; o <<= 1)
            #pragma unroll
            for (int mi = 0; mi < 4; ++mi)
                #pragma unroll
                for (int r = 0; r < 4; ++r) {
                    psum[mi][r] += __shfl_xor(psum[mi][r], o);
                    psq[mi][r]  += __shfl_xor(psq[mi][r], o);
                }
        if (c16 == 0) {
            #pragma unroll
            for (int mi = 0; mi < 4; ++mi)
                #pragma unroll
                for (int r = 0; r < 4; ++r) {
                    int rl = mi * 16 + g4 * 4 + r;
                    lnred[wn][wm][rl][0] = psum[mi][r];
                    lnred[wn][wm][rl][1] = psq[mi][r];
                }
        }
        __syncthreads();
        float gl[4], bl[4];
        #pragma unroll
        for (int ni = 0; ni < 4; ++ni) {
            int col = wn * 64 + ni * 16 + c16;
            gl[ni] = lng[col]; bl[ni] = lnb[col];
        }
        #pragma unroll
        for (int mi = 0; mi < 4; ++mi)
            #pragma unroll
            for (int r = 0; r < 4; ++r) {
                int rl = mi * 16 + g4 * 4 + r;
                int m = m0 + wm * 64 + rl;
                int dst = src_index(m);
                float s = lnred[0][wm][rl][0] + lnred[1][wm][rl][0];
                float q = lnred[0][wm][rl][1] + lnred[1][wm][rl][1];
                float mean = s * (1.f / CH);
                float var  = q * (1.f / CH) - mean * mean;
                float rstd = rsqrtf(var + LNEPS);
                #pragma unroll
                for (int ni = 0; ni < 4; ++ni) {
                    int col = wn * 64 + ni * 16 + c16;
                    float v = acc[mi][ni][r];
                    ((float*)outp)[(size_t)dst * CH + col] = v;
                    ln_out[(size_t)dst * CH + col] = f2bf((v - mean) * rstd * gl[ni] + bl[ni]);
                }
            }
    } else {
        #pragma unroll
        for (int mi = 0; mi < 4; ++mi) {
            #pragma unroll
            for (int r = 0; r < 4; ++r) {
                int m = m0 + wm * 64 + mi * 16 + g4 * 4 + r;
                #pragma unroll
                for (int ni = 0; ni < 4; ++ni) {
                    int col = n0 + wn * 64 + ni * 16 + c16;
                    float v = acc[mi][ni][r];
                    if (EPI == 1) {
                        v += bias[col] * (col < 128 ? QSCALE : 1.f);
                        ((u16*)outp)[(size_t)m * Nn + col] = f2bf(v);
                    } else if (EPI == 3) {
                        v += bias[col];
                        v = 0.5f * v * (1.f + erff(v * 0.70710678118654752f));
                        ((u16*)outp)[(size_t)m * Nn + col] = f2bf(v);
                    } else {
                        v += bias[col];
                        ((float*)outp)[(size_t)m * CH + col] = v + resid[(size_t)m * CH + col];
                    }
                }
            }
        }
    }
}

// ---- bias+mask table, f32, MFMA C-fragment layout: [hw][t][nt=26][lane][r] ----
__global__ __launch_bounds__(64) void bias_k(
    const float* __restrict__ rpb, float* __restrict__ biasT2)
{
    int nt = blockIdx.x;   // 0..25 (col tile; 25 is all -100 pad)
    int t  = blockIdx.y;   // 0..24 (row tile)
    int hw = blockIdx.z;   // head*4 + wt
    int l  = threadIdx.x;  // 0..63
    int head = hw >> 2, wt = hw & 3;
    int bh7 = wt >> 1, bw7 = wt & 1;
    int j = nt * 16 + (l & 15);
    int rb = t * 16 + (l >> 4) * 4;
    f32x4 outv;
    #pragma unroll
    for (int r = 0; r < 4; ++r) {
        int i = rb + r; if (i > NTOK - 1) i = NTOK - 1;
        float v;
        if (j >= NTOK) v = -100.f;
        else {
            int di = i / 49, ri = i - di * 49, hi = ri / 7, wi = ri - hi * 7;
            int dj = j / 49, rj = j - dj * 49, hj = rj / 7, wj = rj - hj * 7;
            int bidx = (di - dj + 7) * 169 + (hi - hj + 6) * 13 + (wi - wj + 6);
            v = rpb[bidx * NHEADS + head];
            int regi = (bh7 ? (hi < 4 ? 1 : 2) : 0) * 3 + (bw7 ? (wi < 4 ? 1 : 2) : 0);
            int regj = (bh7 ? (hj < 4 ? 1 : 2) : 0) * 3 + (bw7 ? (wj < 4 ? 1 : 2) : 0);
            if (regi != regj) v -= 100.f;
        }
        outv[r] = v;
    }
    *(f32x4*)&biasT2[((((size_t)hw * 25 + t) * 26 + nt) << 8) + (l << 2)] = outv;
}

// ---- flash-strip MFMA attention, no-max softmax, bias in MFMA C-operand ----
__global__ __launch_bounds__(256, 2) void attn_mfma(
    const u16* __restrict__ Qb, const float* __restrict__ biasT2,
    u16* __restrict__ O)
{
    __shared__ u16 Kb[416][40];      // 33280 B
    __shared__ u16 Vt[32][420];      // 26880 B
    __shared__ u16 Pst[4][16][40];   // 5120 B

    int bid = blockIdx.x;
    int win = bid >> 2, head = bid & 3;
    int tid = threadIdx.x, w = tid >> 6, l = tid & 63;
    int c16 = l & 15, g4 = l >> 4;

    const size_t qbase = (size_t)win * NTOK * 384;
    for (int e = tid; e < 1600; e += 256) {
        int j = e >> 2, d0 = (e & 3) * 8;
        u16x8 kv = {0, 0, 0, 0, 0, 0, 0, 0};
        u16x8 vv = {0, 0, 0, 0, 0, 0, 0, 0};
        if (j < NTOK) {
            kv = *(const u16x8*)&Qb[qbase + (size_t)j * 384 + 128 + head * 32 + d0];
            vv = *(const u16x8*)&Qb[qbase + (size_t)j * 384 + 256 + head * 32 + d0];
        }
        *(u16x8*)&Kb[j][d0] = kv;
        #pragma unroll
        for (int i = 0; i < 8; ++i) Vt[d0 + i][j] = vv[i];
    }
    for (int e = tid; e < 16 * 32; e += 256)
        Kb[400 + (e >> 5)][e & 31] = 0;
    for (int e = tid; e < 32 * 16; e += 256)
        Vt[e >> 4][400 + (e & 15)] = 0;
    __syncthreads();

    int wIdx = win & 63;
    int wt = (((wIdx >> 3) == 7) ? 2 : 0) + (((wIdx & 7) == 7) ? 1 : 0);
    const float* bt = biasT2 + (((size_t)(head * 4 + wt) * 25 * 26) << 8) + (l << 2);
    u16 (*myP)[40] = Pst[w];

    for (int t = w; t < 25; t += 4) {
        int row0 = t * 16;
        int qr = row0 + c16; if (qr > NTOK - 1) qr = NTOK - 1;
        s16x8 afrag = __builtin_bit_cast(s16x8,
            *(const u16x8*)&Qb[qbase + (size_t)qr * 384 + head * 32 + g4 * 8]);
        const float* btt = bt + (((size_t)t * 26) << 8);

        float l4[4] = {0.f, 0.f, 0.f, 0.f};
        f32x4 oacc[2] = {{0.f,0.f,0.f,0.f},{0.f,0.f,0.f,0.f}};

        for (int jb = 0; jb < 13; ++jb) {
            f32x4 s[2];
            #pragma unroll
            for (int kk = 0; kk < 2; ++kk) {
                f32x4 cb = *(const f32x4*)(btt + (((size_t)(jb * 2 + kk)) << 8));
                s16x8 bfrag = __builtin_bit_cast(s16x8,
                    *(const u16x8*)&Kb[(jb * 2 + kk) * 16 + c16][g4 * 8]);
                s[kk] = mfma16(afrag, bfrag, cb);
            }
            #pragma unroll
            for (int kk = 0; kk < 2; ++kk)
                #pragma unroll
                for (int r = 0; r < 4; ++r) {
                    float p = exp2f(s[kk][r] * 1.44269504f);
                    l4[r] += p;
                    myP[g4 * 4 + r][kk * 16 + c16] = f2bf(p);
                }
            s16x8 pa = __builtin_bit_cast(s16x8, *(const u16x8*)&myP[c16][g4 * 8]);
            #pragma unroll
            for (int nd = 0; nd < 2; ++nd) {
                s16x8 vb = __builtin_bit_cast(s16x8,
                    *(const u16x8*)&Vt[nd * 16 + c16][jb * 32 + g4 * 8]);
                oacc[nd] = mfma16(pa, vb, oacc[nd]);
            }
        }

        #pragma unroll
        for (int r = 0; r < 4; ++r) {
            #pragma unroll
            for (int o = 1; o <= 8; o <<= 1)
                l4[r] += __shfl_xor(l4[r], o);
            l4[r] = 1.f / l4[r];
        }

        #pragma unroll
        for (int nd = 0; nd < 2; ++nd)
            #pragma unroll
            for (int r = 0; r < 4; ++r) {
                int qrow = row0 + g4 * 4 + r;
                if (qrow < NTOK)
                    O[((size_t)(win * NTOK + qrow)) * CH + head * 32 + nd * 16 + c16]
                        = f2bf(oacc[nd][r] * l4[r]);
            }
    }
}

extern "C" void kernel_launch(void* const* d_in, const int* in_sizes, int n_in,
                              void* d_out, int out_size, void* d_ws, size_t ws_size,
                              hipStream_t stream) {
    const float* x      = (const float*)d_in[0];
    const float* n1g    = (const float*)d_in[1];
    const float* n1b    = (const float*)d_in[2];
    const float* qkv_w  = (const float*)d_in[3];
    const float* qkv_b  = (const float*)d_in[4];
    const float* proj_w = (const float*)d_in[5];
    const float* proj_b = (const float*)d_in[6];
    const float* rpb    = (const float*)d_in[7];
    const float* n2g    = (const float*)d_in[8];
    const float* n2b    = (const float*)d_in[9];
    const float* fc1_w  = (const float*)d_in[10];
    const float* fc1_b  = (const float*)d_in[11];
    const float* fc2_w  = (const float*)d_in[12];
    const float* fc2_b  = (const float*)d_in[13];
    float* out = (float*)d_out;

    char* ws = (char*)d_ws;
    size_t off = 0;
    u16* A_bf  = (u16*)(ws + off);  off += (size_t)TOK * 128 * 2;
    u16* Qb_bf = (u16*)(ws + off);  off += (size_t)TOK * 384 * 2;
    u16* O_bf  = (u16*)(ws + off);  off += (size_t)TOK * 128 * 2;
    float* R   = (float*)(ws + off); off += (size_t)TOK * 128 * 4;
    u16* qkvT  = (u16*)(ws + off);  off += 384 * 128 * 2;
    u16* projT = (u16*)(ws + off);  off += 128 * 128 * 2;
    u16* fc1T  = (u16*)(ws + off);  off += 512 * 128 * 2;
    u16* fc2T  = (u16*)(ws + off);  off += 128 * 512 * 2;
    u16* H_bf  = Qb_bf;             // overlays Qb+O exactly; both dead by fc1
    float* biasT2 = (float*)A_bf;   // overlay; A_bf dead after qkv GEMM,
                                    // rewritten by proj's fused LN2

    // 0. weight transposes (+bf16), QSCALE folded into Wq
    hipLaunchKernelGGL(convT, dim3(384/32, 128/32), dim3(256), 0, stream, qkv_w,  qkvT, 128, 384, 128);
    hipLaunchKernelGGL(convT, dim3(128/32, 128/32), dim3(256), 0, stream, proj_w, projT, 128, 128, 0);
    hipLaunchKernelGGL(convT, dim3(512/32, 128/32), dim3(256), 0, stream, fc1_w,  fc1T, 128, 512, 0);
    hipLaunchKernelGGL(convT, dim3(128/32, 512/32), dim3(256), 0, stream, fc2_w,  fc2T, 512, 128, 0);
    // 1. LN1 + shift + window_partition -> bf16
    hipLaunchKernelGGL(ln_kernel, dim3(TOK), dim3(128), 0, stream, x, n1g, n1b, A_bf);
    // 2. qkv GEMM -> bf16
    hipLaunchKernelGGL((gemm_mfma<1, 128>), dim3(3, TOK/128), dim3(256), 0, stream,
                       A_bf, qkvT, qkv_b, Qb_bf, 384, nullptr, nullptr, nullptr, nullptr);
    // 2b. bias+mask table (A_bf dead; overlay)
    hipLaunchKernelGGL(bias_k, dim3(26, 25, 16), dim3(64), 0, stream, rpb, biasT2);
    // 3. flash MFMA windowed attention -> bf16
    hipLaunchKernelGGL(attn_mfma, dim3(NWIN * NHEADS), dim3(256), 0, stream,
                       Qb_bf, biasT2, O_bf);
    // 4. proj GEMM + unshift + residual -> f32 R, fused LN2 -> bf16 A_bf
    hipLaunchKernelGGL((gemm_mfma<2, 128>), dim3(1, TOK/128), dim3(256), 0, stream,
                       O_bf, projT, proj_b, R, 128, x, n2g, n2b, A_bf);
    // 5. fc1 + GELU -> bf16
    hipLaunchKernelGGL((gemm_mfma<3, 128>), dim3(4, TOK/128), dim3(256), 0, stream,
                       A_bf, fc1T, fc1_b, H_bf, 512, nullptr, nullptr, nullptr, nullptr);
    // 6. fc2 + residual -> f32 out
    hipLaunchKernelGGL((gemm_mfma<4, 512>), dim3(1, TOK/128), dim3(256), 0, stream,
                       H_bf, fc2T, fc2_b, out, 128, R, nullptr, nullptr, nullptr);
}

// Round 8
// 182.904 us; speedup vs baseline: 1.3805x; 1.1135x over previous
//
#include <hip/hip_runtime.h>
#include <math.h>

// ---- problem constants ----
#define TOK    50176      // 2*8*56*56 tokens
#define CH     128
#define NWIN   128        // B * 64 windows
#define NTOK   392        // 8*7*7 tokens per window
#define NHEADS 4
#define QSCALE 0.17677669529663687f   // 32^-0.5
#define LNEPS  1e-3f

typedef unsigned short u16;
typedef u16   u16x4  __attribute__((ext_vector_type(4)));
typedef u16   u16x8  __attribute__((ext_vector_type(8)));
typedef short s16x8  __attribute__((ext_vector_type(8)));
typedef float f32x4  __attribute__((ext_vector_type(4)));

__device__ __forceinline__ float bf2f(u16 u) {
    return __uint_as_float(((unsigned)u) << 16);
}
__device__ __forceinline__ u16 f2bf(float f) {
    unsigned u = __float_as_uint(f);
    return (u16)((u + 0x7fffu + ((u >> 16) & 1u)) >> 16);
}
__device__ __forceinline__ f32x4 mfma16(s16x8 a, s16x8 b, f32x4 c) {
    return __builtin_amdgcn_mfma_f32_16x16x32_bf16(a, b, c, 0, 0, 0);
}

// token m in window layout -> flat token index in original layout (+3 roll)
__device__ __forceinline__ int src_index(int m) {
    int b = m / NTOK, t = m - b * NTOK;
    int batch = b >> 6, wIdx = b & 63;
    int bh = wIdx >> 3, bw = wIdx & 7;
    int d = t / 49, rem = t - d * 49;
    int h7 = rem / 7, w7 = rem - h7 * 7;
    int h = bh * 7 + h7 + 3; if (h >= 56) h -= 56;
    int w = bw * 7 + w7 + 3; if (w >= 56) w -= 56;
    return ((batch * 8 + d) * 56 + h) * 56 + w;
}

// ---- weight transpose + f32->bf16 convert: dst[n][k] = src[k][n] * sc ----
__global__ __launch_bounds__(256) void convT(
    const float* __restrict__ src, u16* __restrict__ dst,
    int K, int N, int scaleN)
{
    __shared__ float t[32][33];
    int n0 = blockIdx.x * 32, k0 = blockIdx.y * 32;
    int tx = threadIdx.x & 31, ty = threadIdx.x >> 5;   // ty 0..7
    #pragma unroll
    for (int r = 0; r < 4; ++r)
        t[ty + r * 8][tx] = src[(size_t)(k0 + ty + r * 8) * N + n0 + tx];
    __syncthreads();
    #pragma unroll
    for (int r = 0; r < 4; ++r) {
        int n = n0 + ty + r * 8;
        float sc = (n < scaleN) ? QSCALE : 1.f;
        dst[(size_t)n * K + k0 + tx] = f2bf(t[tx][ty + r * 8] * sc);
    }
}

// ---- LN1: gather f32 x via src_index, LN, -> bf16 window layout ----
__global__ __launch_bounds__(128) void ln_kernel(
    const float* __restrict__ xin,
    const float* __restrict__ g, const float* __restrict__ bta,
    u16* __restrict__ out)
{
    int m = blockIdx.x, c = threadIdx.x;
    float v = xin[(size_t)src_index(m) * CH + c];
    float s1 = v, s2 = v * v;
    #pragma unroll
    for (int o = 32; o; o >>= 1) { s1 += __shfl_xor(s1, o); s2 += __shfl_xor(s2, o); }
    __shared__ float ps[2][2];
    int w = c >> 6;
    if ((c & 63) == 0) { ps[w][0] = s1; ps[w][1] = s2; }
    __syncthreads();
    s1 = ps[0][0] + ps[1][0];
    s2 = ps[0][1] + ps[1][1];
    float mean = s1 * (1.f / CH);
    float var  = s2 * (1.f / CH) - mean * mean;
    float r = rsqrtf(var + LNEPS);
    out[(size_t)m * CH + c] = f2bf((v - mean) * r * g[c] + bta[c]);
}

// ---- MFMA GEMM, BM=64 x BN=128, 512 threads (8 waves = 4m x 2n), BK=128 ----
// C[M][N] = A[M][K]_bf16 * W[N][K]_bf16 + bias
// EPI 1: qkv -> bf16 (bias QSCALE'd for n<128)
// EPI 2: proj + residual scatter -> f32 R, FUSED LN2 -> bf16 ln_out
// EPI 3: gelu -> bf16
// EPI 4: fc2 + resid f32 -> f32 out
template<int EPI, int KTOT>
__global__ __launch_bounds__(512, 6) void gemm_mfma(
    const u16* __restrict__ A, const u16* __restrict__ W,
    const float* __restrict__ bias, void* __restrict__ outp,
    int Nn, const float* __restrict__ resid,
    const float* __restrict__ lng, const float* __restrict__ lnb,
    u16* __restrict__ ln_out)
{
    __shared__ u16 As[4][64][32];        // 16 KB  [kc][row][k32]
    __shared__ u16 Bs[4][128][32];       // 32 KB
    __shared__ float lnred[2][4][16][2]; // [wn][wm][rl][sum,sq]  1 KB

    int tid = threadIdx.x, w = tid >> 6, l = tid & 63;
    int c16 = l & 15, g4 = l >> 4;
    int m0 = blockIdx.y * 64, n0 = blockIdx.x * 128;
    int wm = w & 3, wn = w >> 2;
    const int NCH = KTOT / 128;

    f32x4 acc[4] = {};
    u16x8 va[2], vb[4];

    #pragma unroll
    for (int p = 0; p < 2; ++p) {
        int e = tid + p * 512, row = e >> 4, c8 = e & 15;
        va[p] = *(const u16x8*)&A[(size_t)(m0 + row) * KTOT + c8 * 8];
    }
    #pragma unroll
    for (int p = 0; p < 4; ++p) {
        int e = tid + p * 512, row = e >> 4, c8 = e & 15;
        vb[p] = *(const u16x8*)&W[(size_t)(n0 + row) * KTOT + c8 * 8];
    }
    for (int ch = 0; ch < NCH; ++ch) {
        #pragma unroll
        for (int p = 0; p < 2; ++p) {
            int e = tid + p * 512, row = e >> 4, c8 = e & 15;
            *(u16x8*)&As[c8 >> 2][row][(c8 & 3) * 8] = va[p];
        }
        #pragma unroll
        for (int p = 0; p < 4; ++p) {
            int e = tid + p * 512, row = e >> 4, c8 = e & 15;
            *(u16x8*)&Bs[c8 >> 2][row][(c8 & 3) * 8] = vb[p];
        }
        __syncthreads();
        if (ch + 1 < NCH) {
            #pragma unroll
            for (int p = 0; p < 2; ++p) {
                int e = tid + p * 512, row = e >> 4, c8 = e & 15;
                va[p] = *(const u16x8*)&A[(size_t)(m0 + row) * KTOT + (ch + 1) * 128 + c8 * 8];
            }
            #pragma unroll
            for (int p = 0; p < 4; ++p) {
                int e = tid + p * 512, row = e >> 4, c8 = e & 15;
                vb[p] = *(const u16x8*)&W[(size_t)(n0 + row) * KTOT + (ch + 1) * 128 + c8 * 8];
            }
        }
        #pragma unroll
        for (int kc = 0; kc < 4; ++kc) {
            s16x8 af = __builtin_bit_cast(s16x8,
                *(const u16x8*)&As[kc][wm * 16 + c16][g4 * 8]);
            #pragma unroll
            for (int ni = 0; ni < 4; ++ni) {
                s16x8 bf = __builtin_bit_cast(s16x8,
                    *(const u16x8*)&Bs[kc][wn * 64 + ni * 16 + c16][g4 * 8]);
                acc[ni] = mfma16(af, bf, acc[ni]);
            }
        }
        if (ch + 1 < NCH) __syncthreads();
    }

    if (EPI == 2) {
        float psum[4], psq[4];
        int dstl[4];
        #pragma unroll
        for (int r = 0; r < 4; ++r) {
            int m = m0 + wm * 16 + g4 * 4 + r;
            int dst = src_index(m);
            dstl[r] = dst;
            float s = 0.f, q = 0.f;
            #pragma unroll
            for (int ni = 0; ni < 4; ++ni) {
                int col = wn * 64 + ni * 16 + c16;
                float v = acc[ni][r] + bias[col] + resid[(size_t)dst * CH + col];
                acc[ni][r] = v;
                s += v; q += v * v;
            }
            psum[r] = s; psq[r] = q;
        }
        #pragma unroll
        for (int o = 1; o <= 8; o <<= 1)
            #pragma unroll
            for (int r = 0; r < 4; ++r) {
                psum[r] += __shfl_xor(psum[r], o);
                psq[r]  += __shfl_xor(psq[r], o);
            }
        if (c16 == 0) {
            #pragma unroll
            for (int r = 0; r < 4; ++r) {
                int rl = g4 * 4 + r;
                lnred[wn][wm][rl][0] = psum[r];
                lnred[wn][wm][rl][1] = psq[r];
            }
        }
        __syncthreads();
        float gl[4], bl[4];
        #pragma unroll
        for (int ni = 0; ni < 4; ++ni) {
            int col = wn * 64 + ni * 16 + c16;
            gl[ni] = lng[col]; bl[ni] = lnb[col];
        }
        #pragma unroll
        for (int r = 0; r < 4; ++r) {
            int rl = g4 * 4 + r;
            float s = lnred[0][wm][rl][0] + lnred[1][wm][rl][0];
            float q = lnred[0][wm][rl][1] + lnred[1][wm][rl][1];
            float mean = s * (1.f / CH);
            float var  = q * (1.f / CH) - mean * mean;
            float rstd = rsqrtf(var + LNEPS);
            int dst = dstl[r];
            #pragma unroll
            for (int ni = 0; ni < 4; ++ni) {
                int col = wn * 64 + ni * 16 + c16;
                float v = acc[ni][r];
                ((float*)outp)[(size_t)dst * CH + col] = v;
                ln_out[(size_t)dst * CH + col] = f2bf((v - mean) * rstd * gl[ni] + bl[ni]);
            }
        }
    } else {
        #pragma unroll
        for (int r = 0; r < 4; ++r) {
            int m = m0 + wm * 16 + g4 * 4 + r;
            #pragma unroll
            for (int ni = 0; ni < 4; ++ni) {
                int col = n0 + wn * 64 + ni * 16 + c16;
                float v = acc[ni][r];
                if (EPI == 1) {
                    v += bias[col] * (col < 128 ? QSCALE : 1.f);
                    ((u16*)outp)[(size_t)m * Nn + col] = f2bf(v);
                } else if (EPI == 3) {
                    v += bias[col];
                    v = 0.5f * v * (1.f + erff(v * 0.70710678118654752f));
                    ((u16*)outp)[(size_t)m * Nn + col] = f2bf(v);
                } else {
                    v += bias[col];
                    ((float*)outp)[(size_t)m * CH + col] = v + resid[(size_t)m * CH + col];
                }
            }
        }
    }
}

// ---- bias+mask table, f32, MFMA C-fragment layout: [hw][t][nt=26][lane][r] ----
__global__ __launch_bounds__(64) void bias_k(
    const float* __restrict__ rpb, float* __restrict__ biasT2)
{
    int nt = blockIdx.x;   // 0..25 (col tile; 25 is all -100 pad)
    int t  = blockIdx.y;   // 0..24 (row tile)
    int hw = blockIdx.z;   // head*4 + wt
    int l  = threadIdx.x;  // 0..63
    int head = hw >> 2, wt = hw & 3;
    int bh7 = wt >> 1, bw7 = wt & 1;
    int j = nt * 16 + (l & 15);
    int rb = t * 16 + (l >> 4) * 4;
    f32x4 outv;
    #pragma unroll
    for (int r = 0; r < 4; ++r) {
        int i = rb + r; if (i > NTOK - 1) i = NTOK - 1;
        float v;
        if (j >= NTOK) v = -100.f;
        else {
            int di = i / 49, ri = i - di * 49, hi = ri / 7, wi = ri - hi * 7;
            int dj = j / 49, rj = j - dj * 49, hj = rj / 7, wj = rj - hj * 7;
            int bidx = (di - dj + 7) * 169 + (hi - hj + 6) * 13 + (wi - wj + 6);
            v = rpb[bidx * NHEADS + head];
            int regi = (bh7 ? (hi < 4 ? 1 : 2) : 0) * 3 + (bw7 ? (wi < 4 ? 1 : 2) : 0);
            int regj = (bh7 ? (hj < 4 ? 1 : 2) : 0) * 3 + (bw7 ? (wj < 4 ? 1 : 2) : 0);
            if (regi != regj) v -= 100.f;
        }
        outv[r] = v;
    }
    *(f32x4*)&biasT2[((((size_t)hw * 25 + t) * 26 + nt) << 8) + (l << 2)] = outv;
}

// ---- flash-strip MFMA attention, no-max softmax, bias in MFMA C-operand ----
__global__ __launch_bounds__(256, 2) void attn_mfma(
    const u16* __restrict__ Qb, const float* __restrict__ biasT2,
    u16* __restrict__ O)
{
    __shared__ u16 Kb[416][40];      // 33280 B
    __shared__ u16 Vt[32][420];      // 26880 B
    __shared__ u16 Pst[4][16][40];   // 5120 B

    int bid = blockIdx.x;
    int win = bid >> 2, head = bid & 3;
    int tid = threadIdx.x, w = tid >> 6, l = tid & 63;
    int c16 = l & 15, g4 = l >> 4;

    const size_t qbase = (size_t)win * NTOK * 384;
    for (int e = tid; e < 1600; e += 256) {
        int j = e >> 2, d0 = (e & 3) * 8;
        u16x8 kv = {0, 0, 0, 0, 0, 0, 0, 0};
        u16x8 vv = {0, 0, 0, 0, 0, 0, 0, 0};
        if (j < NTOK) {
            kv = *(const u16x8*)&Qb[qbase + (size_t)j * 384 + 128 + head * 32 + d0];
            vv = *(const u16x8*)&Qb[qbase + (size_t)j * 384 + 256 + head * 32 + d0];
        }
        *(u16x8*)&Kb[j][d0] = kv;
        #pragma unroll
        for (int i = 0; i < 8; ++i) Vt[d0 + i][j] = vv[i];
    }
    for (int e = tid; e < 16 * 32; e += 256)
        Kb[400 + (e >> 5)][e & 31] = 0;
    for (int e = tid; e < 32 * 16; e += 256)
        Vt[e >> 4][400 + (e & 15)] = 0;
    __syncthreads();

    int wIdx = win & 63;
    int wt = (((wIdx >> 3) == 7) ? 2 : 0) + (((wIdx & 7) == 7) ? 1 : 0);
    const float* bt = biasT2 + (((size_t)(head * 4 + wt) * 25 * 26) << 8) + (l << 2);
    u16 (*myP)[40] = Pst[w];

    for (int t = w; t < 25; t += 4) {
        int row0 = t * 16;
        int qr = row0 + c16; if (qr > NTOK - 1) qr = NTOK - 1;
        s16x8 afrag = __builtin_bit_cast(s16x8,
            *(const u16x8*)&Qb[qbase + (size_t)qr * 384 + head * 32 + g4 * 8]);
        const float* btt = bt + (((size_t)t * 26) << 8);

        float l4[4] = {0.f, 0.f, 0.f, 0.f};
        f32x4 oacc[2] = {{0.f,0.f,0.f,0.f},{0.f,0.f,0.f,0.f}};

        for (int jb = 0; jb < 13; ++jb) {
            f32x4 s[2];
            #pragma unroll
            for (int kk = 0; kk < 2; ++kk) {
                f32x4 cb = *(const f32x4*)(btt + (((size_t)(jb * 2 + kk)) << 8));
                s16x8 bfrag = __builtin_bit_cast(s16x8,
                    *(const u16x8*)&Kb[(jb * 2 + kk) * 16 + c16][g4 * 8]);
                s[kk] = mfma16(afrag, bfrag, cb);
            }
            #pragma unroll
            for (int kk = 0; kk < 2; ++kk)
                #pragma unroll
                for (int r = 0; r < 4; ++r) {
                    float p = exp2f(s[kk][r] * 1.44269504f);
                    l4[r] += p;
                    myP[g4 * 4 + r][kk * 16 + c16] = f2bf(p);
                }
            s16x8 pa = __builtin_bit_cast(s16x8, *(const u16x8*)&myP[c16][g4 * 8]);
            #pragma unroll
            for (int nd = 0; nd < 2; ++nd) {
                s16x8 vb = __builtin_bit_cast(s16x8,
                    *(const u16x8*)&Vt[nd * 16 + c16][jb * 32 + g4 * 8]);
                oacc[nd] = mfma16(pa, vb, oacc[nd]);
            }
        }

        #pragma unroll
        for (int r = 0; r < 4; ++r) {
            #pragma unroll
            for (int o = 1; o <= 8; o <<= 1)
                l4[r] += __shfl_xor(l4[r], o);
            l4[r] = 1.f / l4[r];
        }

        #pragma unroll
        for (int nd = 0; nd < 2; ++nd)
            #pragma unroll
            for (int r = 0; r < 4; ++r) {
                int qrow = row0 + g4 * 4 + r;
                if (qrow < NTOK)
                    O[((size_t)(win * NTOK + qrow)) * CH + head * 32 + nd * 16 + c16]
                        = f2bf(oacc[nd][r] * l4[r]);
            }
    }
}

extern "C" void kernel_launch(void* const* d_in, const int* in_sizes, int n_in,
                              void* d_out, int out_size, void* d_ws, size_t ws_size,
                              hipStream_t stream) {
    const float* x      = (const float*)d_in[0];
    const float* n1g    = (const float*)d_in[1];
    const float* n1b    = (const float*)d_in[2];
    const float* qkv_w  = (const float*)d_in[3];
    const float* qkv_b  = (const float*)d_in[4];
    const float* proj_w = (const float*)d_in[5];
    const float* proj_b = (const float*)d_in[6];
    const float* rpb    = (const float*)d_in[7];
    const float* n2g    = (const float*)d_in[8];
    const float* n2b    = (const float*)d_in[9];
    const float* fc1_w  = (const float*)d_in[10];
    const float* fc1_b  = (const float*)d_in[11];
    const float* fc2_w  = (const float*)d_in[12];
    const float* fc2_b  = (const float*)d_in[13];
    float* out = (float*)d_out;

    char* ws = (char*)d_ws;
    size_t off = 0;
    u16* A_bf  = (u16*)(ws + off);  off += (size_t)TOK * 128 * 2;
    u16* Qb_bf = (u16*)(ws + off);  off += (size_t)TOK * 384 * 2;
    u16* O_bf  = (u16*)(ws + off);  off += (size_t)TOK * 128 * 2;
    float* R   = (float*)(ws + off); off += (size_t)TOK * 128 * 4;
    u16* qkvT  = (u16*)(ws + off);  off += 384 * 128 * 2;
    u16* projT = (u16*)(ws + off);  off += 128 * 128 * 2;
    u16* fc1T  = (u16*)(ws + off);  off += 512 * 128 * 2;
    u16* fc2T  = (u16*)(ws + off);  off += 128 * 512 * 2;
    u16* H_bf  = Qb_bf;             // overlays Qb+O exactly; both dead by fc1
    float* biasT2 = (float*)A_bf;   // overlay; A_bf dead after qkv GEMM,
                                    // rewritten by proj's fused LN2

    // 0. weight transposes (+bf16), QSCALE folded into Wq
    hipLaunchKernelGGL(convT, dim3(384/32, 128/32), dim3(256), 0, stream, qkv_w,  qkvT, 128, 384, 128);
    hipLaunchKernelGGL(convT, dim3(128/32, 128/32), dim3(256), 0, stream, proj_w, projT, 128, 128, 0);
    hipLaunchKernelGGL(convT, dim3(512/32, 128/32), dim3(256), 0, stream, fc1_w,  fc1T, 128, 512, 0);
    hipLaunchKernelGGL(convT, dim3(128/32, 512/32), dim3(256), 0, stream, fc2_w,  fc2T, 512, 128, 0);
    // 1. LN1 + shift + window_partition -> bf16
    hipLaunchKernelGGL(ln_kernel, dim3(TOK), dim3(128), 0, stream, x, n1g, n1b, A_bf);
    // 2. qkv GEMM -> bf16
    hipLaunchKernelGGL((gemm_mfma<1, 128>), dim3(3, TOK/64), dim3(512), 0, stream,
                       A_bf, qkvT, qkv_b, Qb_bf, 384, nullptr, nullptr, nullptr, nullptr);
    // 2b. bias+mask table (A_bf dead; overlay)
    hipLaunchKernelGGL(bias_k, dim3(26, 25, 16), dim3(64), 0, stream, rpb, biasT2);
    // 3. flash MFMA windowed attention -> bf16
    hipLaunchKernelGGL(attn_mfma, dim3(NWIN * NHEADS), dim3(256), 0, stream,
                       Qb_bf, biasT2, O_bf);
    // 4. proj GEMM + unshift + residual -> f32 R, fused LN2 -> bf16 A_bf
    hipLaunchKernelGGL((gemm_mfma<2, 128>), dim3(1, TOK/64), dim3(512), 0, stream,
                       O_bf, projT, proj_b, R, 128, x, n2g, n2b, A_bf);
    // 5. fc1 + GELU -> bf16
    hipLaunchKernelGGL((gemm_mfma<3, 128>), dim3(4, TOK/64), dim3(512), 0, stream,
                       A_bf, fc1T, fc1_b, H_bf, 512, nullptr, nullptr, nullptr, nullptr);
    // 6. fc2 + residual -> f32 out
    hipLaunchKernelGGL((gemm_mfma<4, 512>), dim3(1, TOK/64), dim3(512), 0, stream,
                       H_bf, fc2T, fc2_b, out, 128, R, nullptr, nullptr, nullptr);
}

// Round 9
// 178.644 us; speedup vs baseline: 1.4134x; 1.0238x over previous
//
#include <hip/hip_runtime.h>
#include <math.h>

// ---- problem constants ----
#define TOK    50176      // 2*8*56*56 tokens
#define CH     128
#define NWIN   128        // B * 64 windows
#define NTOK   392        // 8*7*7 tokens per window
#define NHEADS 4
#define QSCALE 0.17677669529663687f   // 32^-0.5
#define LNEPS  1e-3f

typedef unsigned short u16;
typedef u16   u16x4  __attribute__((ext_vector_type(4)));
typedef u16   u16x8  __attribute__((ext_vector_type(8)));
typedef short s16x8  __attribute__((ext_vector_type(8)));
typedef float f32x4  __attribute__((ext_vector_type(4)));

__device__ __forceinline__ float bf2f(u16 u) {
    return __uint_as_float(((unsigned)u) << 16);
}
__device__ __forceinline__ u16 f2bf(float f) {
    unsigned u = __float_as_uint(f);
    return (u16)((u + 0x7fffu + ((u >> 16) & 1u)) >> 16);
}
__device__ __forceinline__ f32x4 mfma16(s16x8 a, s16x8 b, f32x4 c) {
    return __builtin_amdgcn_mfma_f32_16x16x32_bf16(a, b, c, 0, 0, 0);
}

// token m in window layout -> flat token index in original layout (+3 roll)
__device__ __forceinline__ int src_index(int m) {
    int b = m / NTOK, t = m - b * NTOK;
    int batch = b >> 6, wIdx = b & 63;
    int bh = wIdx >> 3, bw = wIdx & 7;
    int d = t / 49, rem = t - d * 49;
    int h7 = rem / 7, w7 = rem - h7 * 7;
    int h = bh * 7 + h7 + 3; if (h >= 56) h -= 56;
    int w = bw * 7 + w7 + 3; if (w >= 56) w -= 56;
    return ((batch * 8 + d) * 56 + h) * 56 + w;
}

// ---- weight transpose + f32->bf16 convert: dst[n][k] = src[k][n] * sc ----
__global__ __launch_bounds__(256) void convT(
    const float* __restrict__ src, u16* __restrict__ dst,
    int K, int N, int scaleN)
{
    __shared__ float t[32][33];
    int n0 = blockIdx.x * 32, k0 = blockIdx.y * 32;
    int tx = threadIdx.x & 31, ty = threadIdx.x >> 5;   // ty 0..7
    #pragma unroll
    for (int r = 0; r < 4; ++r)
        t[ty + r * 8][tx] = src[(size_t)(k0 + ty + r * 8) * N + n0 + tx];
    __syncthreads();
    #pragma unroll
    for (int r = 0; r < 4; ++r) {
        int n = n0 + ty + r * 8;
        float sc = (n < scaleN) ? QSCALE : 1.f;
        dst[(size_t)n * K + k0 + tx] = f2bf(t[tx][ty + r * 8] * sc);
    }
}

// ---- LN1: gather f32 x via src_index, LN, -> bf16 window layout ----
__global__ __launch_bounds__(128) void ln_kernel(
    const float* __restrict__ xin,
    const float* __restrict__ g, const float* __restrict__ bta,
    u16* __restrict__ out)
{
    int m = blockIdx.x, c = threadIdx.x;
    float v = xin[(size_t)src_index(m) * CH + c];
    float s1 = v, s2 = v * v;
    #pragma unroll
    for (int o = 32; o; o >>= 1) { s1 += __shfl_xor(s1, o); s2 += __shfl_xor(s2, o); }
    __shared__ float ps[2][2];
    int w = c >> 6;
    if ((c & 63) == 0) { ps[w][0] = s1; ps[w][1] = s2; }
    __syncthreads();
    s1 = ps[0][0] + ps[1][0];
    s2 = ps[0][1] + ps[1][1];
    float mean = s1 * (1.f / CH);
    float var  = s2 * (1.f / CH) - mean * mean;
    float r = rsqrtf(var + LNEPS);
    out[(size_t)m * CH + c] = f2bf((v - mean) * r * g[c] + bta[c]);
}

// ---- MFMA GEMM, BM=64 x BN=128, 512 threads (8 waves = 4m x 2n), BK=128 ----
// C[M][N] = A[M][K]_bf16 * W[N][K]_bf16 + bias
// EPI 1: qkv -> bf16 (bias QSCALE'd for n<128)
// EPI 2: proj + residual scatter -> f32 R, FUSED LN2 -> bf16 ln_out
// EPI 3: gelu -> bf16
// EPI 4: fc2 + resid f32 -> f32 out
template<int EPI, int KTOT>
__global__ __launch_bounds__(512, 6) void gemm_mfma(
    const u16* __restrict__ A, const u16* __restrict__ W,
    const float* __restrict__ bias, void* __restrict__ outp,
    int Nn, const float* __restrict__ resid,
    const float* __restrict__ lng, const float* __restrict__ lnb,
    u16* __restrict__ ln_out)
{
    __shared__ u16 As[4][64][32];        // 16 KB  [kc][row][k32]
    __shared__ u16 Bs[4][128][32];       // 32 KB
    __shared__ float lnred[2][4][16][2]; // [wn][wm][rl][sum,sq]  1 KB

    int tid = threadIdx.x, w = tid >> 6, l = tid & 63;
    int c16 = l & 15, g4 = l >> 4;
    int m0 = blockIdx.y * 64, n0 = blockIdx.x * 128;
    int wm = w & 3, wn = w >> 2;
    const int NCH = KTOT / 128;

    f32x4 acc[4] = {};
    u16x8 va[2], vb[4];

    #pragma unroll
    for (int p = 0; p < 2; ++p) {
        int e = tid + p * 512, row = e >> 4, c8 = e & 15;
        va[p] = *(const u16x8*)&A[(size_t)(m0 + row) * KTOT + c8 * 8];
    }
    #pragma unroll
    for (int p = 0; p < 4; ++p) {
        int e = tid + p * 512, row = e >> 4, c8 = e & 15;
        vb[p] = *(const u16x8*)&W[(size_t)(n0 + row) * KTOT + c8 * 8];
    }
    for (int ch = 0; ch < NCH; ++ch) {
        #pragma unroll
        for (int p = 0; p < 2; ++p) {
            int e = tid + p * 512, row = e >> 4, c8 = e & 15;
            *(u16x8*)&As[c8 >> 2][row][(c8 & 3) * 8] = va[p];
        }
        #pragma unroll
        for (int p = 0; p < 4; ++p) {
            int e = tid + p * 512, row = e >> 4, c8 = e & 15;
            *(u16x8*)&Bs[c8 >> 2][row][(c8 & 3) * 8] = vb[p];
        }
        __syncthreads();
        if (ch + 1 < NCH) {
            #pragma unroll
            for (int p = 0; p < 2; ++p) {
                int e = tid + p * 512, row = e >> 4, c8 = e & 15;
                va[p] = *(const u16x8*)&A[(size_t)(m0 + row) * KTOT + (ch + 1) * 128 + c8 * 8];
            }
            #pragma unroll
            for (int p = 0; p < 4; ++p) {
                int e = tid + p * 512, row = e >> 4, c8 = e & 15;
                vb[p] = *(const u16x8*)&W[(size_t)(n0 + row) * KTOT + (ch + 1) * 128 + c8 * 8];
            }
        }
        #pragma unroll
        for (int kc = 0; kc < 4; ++kc) {
            s16x8 af = __builtin_bit_cast(s16x8,
                *(const u16x8*)&As[kc][wm * 16 + c16][g4 * 8]);
            #pragma unroll
            for (int ni = 0; ni < 4; ++ni) {
                s16x8 bf = __builtin_bit_cast(s16x8,
                    *(const u16x8*)&Bs[kc][wn * 64 + ni * 16 + c16][g4 * 8]);
                acc[ni] = mfma16(af, bf, acc[ni]);
            }
        }
        if (ch + 1 < NCH) __syncthreads();
    }

    if (EPI == 2) {
        float psum[4], psq[4];
        int dstl[4];
        #pragma unroll
        for (int r = 0; r < 4; ++r) {
            int m = m0 + wm * 16 + g4 * 4 + r;
            int dst = src_index(m);
            dstl[r] = dst;
            float s = 0.f, q = 0.f;
            #pragma unroll
            for (int ni = 0; ni < 4; ++ni) {
                int col = wn * 64 + ni * 16 + c16;
                float v = acc[ni][r] + bias[col] + resid[(size_t)dst * CH + col];
                acc[ni][r] = v;
                s += v; q += v * v;
            }
            psum[r] = s; psq[r] = q;
        }
        #pragma unroll
        for (int o = 1; o <= 8; o <<= 1)
            #pragma unroll
            for (int r = 0; r < 4; ++r) {
                psum[r] += __shfl_xor(psum[r], o);
                psq[r]  += __shfl_xor(psq[r], o);
            }
        if (c16 == 0) {
            #pragma unroll
            for (int r = 0; r < 4; ++r) {
                int rl = g4 * 4 + r;
                lnred[wn][wm][rl][0] = psum[r];
                lnred[wn][wm][rl][1] = psq[r];
            }
        }
        __syncthreads();
        float gl[4], bl[4];
        #pragma unroll
        for (int ni = 0; ni < 4; ++ni) {
            int col = wn * 64 + ni * 16 + c16;
            gl[ni] = lng[col]; bl[ni] = lnb[col];
        }
        #pragma unroll
        for (int r = 0; r < 4; ++r) {
            int rl = g4 * 4 + r;
            float s = lnred[0][wm][rl][0] + lnred[1][wm][rl][0];
            float q = lnred[0][wm][rl][1] + lnred[1][wm][rl][1];
            float mean = s * (1.f / CH);
            float var  = q * (1.f / CH) - mean * mean;
            float rstd = rsqrtf(var + LNEPS);
            int dst = dstl[r];
            #pragma unroll
            for (int ni = 0; ni < 4; ++ni) {
                int col = wn * 64 + ni * 16 + c16;
                float v = acc[ni][r];
                ((float*)outp)[(size_t)dst * CH + col] = v;
                ln_out[(size_t)dst * CH + col] = f2bf((v - mean) * rstd * gl[ni] + bl[ni]);
            }
        }
    } else {
        #pragma unroll
        for (int r = 0; r < 4; ++r) {
            int m = m0 + wm * 16 + g4 * 4 + r;
            #pragma unroll
            for (int ni = 0; ni < 4; ++ni) {
                int col = n0 + wn * 64 + ni * 16 + c16;
                float v = acc[ni][r];
                if (EPI == 1) {
                    v += bias[col] * (col < 128 ? QSCALE : 1.f);
                    ((u16*)outp)[(size_t)m * Nn + col] = f2bf(v);
                } else if (EPI == 3) {
                    v += bias[col];
                    v = 0.5f * v * (1.f + erff(v * 0.70710678118654752f));
                    ((u16*)outp)[(size_t)m * Nn + col] = f2bf(v);
                } else {
                    v += bias[col];
                    ((float*)outp)[(size_t)m * CH + col] = v + resid[(size_t)m * CH + col];
                }
            }
        }
    }
}

// ---- bias+mask table, f32, MFMA C-fragment layout: [hw][t][nt=26][lane][r] ----
__global__ __launch_bounds__(64) void bias_k(
    const float* __restrict__ rpb, float* __restrict__ biasT2)
{
    int nt = blockIdx.x;   // 0..25 (col tile; 25 is all -100 pad)
    int t  = blockIdx.y;   // 0..24 (row tile)
    int hw = blockIdx.z;   // head*4 + wt
    int l  = threadIdx.x;  // 0..63
    int head = hw >> 2, wt = hw & 3;
    int bh7 = wt >> 1, bw7 = wt & 1;
    int j = nt * 16 + (l & 15);
    int rb = t * 16 + (l >> 4) * 4;
    f32x4 outv;
    #pragma unroll
    for (int r = 0; r < 4; ++r) {
        int i = rb + r; if (i > NTOK - 1) i = NTOK - 1;
        float v;
        if (j >= NTOK) v = -100.f;
        else {
            int di = i / 49, ri = i - di * 49, hi = ri / 7, wi = ri - hi * 7;
            int dj = j / 49, rj = j - dj * 49, hj = rj / 7, wj = rj - hj * 7;
            int bidx = (di - dj + 7) * 169 + (hi - hj + 6) * 13 + (wi - wj + 6);
            v = rpb[bidx * NHEADS + head];
            int regi = (bh7 ? (hi < 4 ? 1 : 2) : 0) * 3 + (bw7 ? (wi < 4 ? 1 : 2) : 0);
            int regj = (bh7 ? (hj < 4 ? 1 : 2) : 0) * 3 + (bw7 ? (wj < 4 ? 1 : 2) : 0);
            if (regi != regj) v -= 100.f;
        }
        outv[r] = v;
    }
    *(f32x4*)&biasT2[((((size_t)hw * 25 + t) * 26 + nt) << 8) + (l << 2)] = outv;
}

// ---- flash-strip MFMA attention, 8 waves/block, K-frags from global/L2 ----
// no-max softmax, bias in MFMA C-operand; LDS = V^T + P strips only (37 KB)
__global__ __launch_bounds__(512, 4) void attn_mfma(
    const u16* __restrict__ Qb, const float* __restrict__ biasT2,
    u16* __restrict__ O)
{
    __shared__ u16 Vt[32][420];      // 26880 B, cols 400..415 zero
    __shared__ u16 Pst[8][16][40];   // 10240 B, per-wave P strip

    int bid = blockIdx.x;
    int win = bid >> 2, head = bid & 3;
    int tid = threadIdx.x, w = tid >> 6, l = tid & 63;
    int c16 = l & 15, g4 = l >> 4;

    const size_t qbase = (size_t)win * NTOK * 384;
    // stage V transposed (K stays in global/L2)
    for (int e = tid; e < 1600; e += 512) {
        int j = e >> 2, d0 = (e & 3) * 8;
        u16x8 vv = {0, 0, 0, 0, 0, 0, 0, 0};
        if (j < NTOK)
            vv = *(const u16x8*)&Qb[qbase + (size_t)j * 384 + 256 + head * 32 + d0];
        #pragma unroll
        for (int i = 0; i < 8; ++i) Vt[d0 + i][j] = vv[i];
    }
    {
        int e = tid;
        if (e < 32 * 16) Vt[e >> 4][400 + (e & 15)] = 0;
    }
    __syncthreads();

    int wIdx = win & 63;
    int wt = (((wIdx >> 3) == 7) ? 2 : 0) + (((wIdx & 7) == 7) ? 1 : 0);
    const float* bt = biasT2 + (((size_t)(head * 4 + wt) * 25 * 26) << 8) + (l << 2);
    u16 (*myP)[40] = Pst[w];
    const u16* kroot = Qb + qbase + 128 + head * 32 + g4 * 8;

    for (int t = w; t < 25; t += 8) {
        int row0 = t * 16;
        int qr = row0 + c16; if (qr > NTOK - 1) qr = NTOK - 1;
        s16x8 afrag = __builtin_bit_cast(s16x8,
            *(const u16x8*)&Qb[qbase + (size_t)qr * 384 + head * 32 + g4 * 8]);
        const float* btt = bt + (((size_t)t * 26) << 8);

        float l4[4] = {0.f, 0.f, 0.f, 0.f};
        f32x4 oacc[2] = {{0.f,0.f,0.f,0.f},{0.f,0.f,0.f,0.f}};

        for (int jb = 0; jb < 13; ++jb) {
            f32x4 s[2];
            #pragma unroll
            for (int kk = 0; kk < 2; ++kk) {
                f32x4 cb = *(const f32x4*)(btt + (((size_t)(jb * 2 + kk)) << 8));
                int kr = jb * 32 + kk * 16 + c16;
                if (kr > NTOK - 1) kr = NTOK - 1;   // pad rows: bias=-100 -> exp2 -> 0
                s16x8 bfrag = __builtin_bit_cast(s16x8,
                    *(const u16x8*)&kroot[(size_t)kr * 384]);
                s[kk] = mfma16(afrag, bfrag, cb);
            }
            #pragma unroll
            for (int kk = 0; kk < 2; ++kk)
                #pragma unroll
                for (int r = 0; r < 4; ++r) {
                    float p = exp2f(s[kk][r] * 1.44269504f);
                    l4[r] += p;
                    myP[g4 * 4 + r][kk * 16 + c16] = f2bf(p);
                }
            s16x8 pa = __builtin_bit_cast(s16x8, *(const u16x8*)&myP[c16][g4 * 8]);
            #pragma unroll
            for (int nd = 0; nd < 2; ++nd) {
                s16x8 vb = __builtin_bit_cast(s16x8,
                    *(const u16x8*)&Vt[nd * 16 + c16][jb * 32 + g4 * 8]);
                oacc[nd] = mfma16(pa, vb, oacc[nd]);
            }
        }

        #pragma unroll
        for (int r = 0; r < 4; ++r) {
            #pragma unroll
            for (int o = 1; o <= 8; o <<= 1)
                l4[r] += __shfl_xor(l4[r], o);
            l4[r] = 1.f / l4[r];
        }

        #pragma unroll
        for (int nd = 0; nd < 2; ++nd)
            #pragma unroll
            for (int r = 0; r < 4; ++r) {
                int qrow = row0 + g4 * 4 + r;
                if (qrow < NTOK)
                    O[((size_t)(win * NTOK + qrow)) * CH + head * 32 + nd * 16 + c16]
                        = f2bf(oacc[nd][r] * l4[r]);
            }
    }
}

extern "C" void kernel_launch(void* const* d_in, const int* in_sizes, int n_in,
                              void* d_out, int out_size, void* d_ws, size_t ws_size,
                              hipStream_t stream) {
    const float* x      = (const float*)d_in[0];
    const float* n1g    = (const float*)d_in[1];
    const float* n1b    = (const float*)d_in[2];
    const float* qkv_w  = (const float*)d_in[3];
    const float* qkv_b  = (const float*)d_in[4];
    const float* proj_w = (const float*)d_in[5];
    const float* proj_b = (const float*)d_in[6];
    const float* rpb    = (const float*)d_in[7];
    const float* n2g    = (const float*)d_in[8];
    const float* n2b    = (const float*)d_in[9];
    const float* fc1_w  = (const float*)d_in[10];
    const float* fc1_b  = (const float*)d_in[11];
    const float* fc2_w  = (const float*)d_in[12];
    const float* fc2_b  = (const float*)d_in[13];
    float* out = (float*)d_out;

    char* ws = (char*)d_ws;
    size_t off = 0;
    u16* A_bf  = (u16*)(ws + off);  off += (size_t)TOK * 128 * 2;
    u16* Qb_bf = (u16*)(ws + off);  off += (size_t)TOK * 384 * 2;
    u16* O_bf  = (u16*)(ws + off);  off += (size_t)TOK * 128 * 2;
    float* R   = (float*)(ws + off); off += (size_t)TOK * 128 * 4;
    u16* qkvT  = (u16*)(ws + off);  off += 384 * 128 * 2;
    u16* projT = (u16*)(ws + off);  off += 128 * 128 * 2;
    u16* fc1T  = (u16*)(ws + off);  off += 512 * 128 * 2;
    u16* fc2T  = (u16*)(ws + off);  off += 128 * 512 * 2;
    u16* H_bf  = Qb_bf;             // overlays Qb+O exactly; both dead by fc1
    float* biasT2 = (float*)A_bf;   // overlay; A_bf dead after qkv GEMM,
                                    // rewritten by proj's fused LN2

    // 0. weight transposes (+bf16), QSCALE folded into Wq
    hipLaunchKernelGGL(convT, dim3(384/32, 128/32), dim3(256), 0, stream, qkv_w,  qkvT, 128, 384, 128);
    hipLaunchKernelGGL(convT, dim3(128/32, 128/32), dim3(256), 0, stream, proj_w, projT, 128, 128, 0);
    hipLaunchKernelGGL(convT, dim3(512/32, 128/32), dim3(256), 0, stream, fc1_w,  fc1T, 128, 512, 0);
    hipLaunchKernelGGL(convT, dim3(128/32, 512/32), dim3(256), 0, stream, fc2_w,  fc2T, 512, 128, 0);
    // 1. LN1 + shift + window_partition -> bf16
    hipLaunchKernelGGL(ln_kernel, dim3(TOK), dim3(128), 0, stream, x, n1g, n1b, A_bf);
    // 2. qkv GEMM -> bf16
    hipLaunchKernelGGL((gemm_mfma<1, 128>), dim3(3, TOK/64), dim3(512), 0, stream,
                       A_bf, qkvT, qkv_b, Qb_bf, 384, nullptr, nullptr, nullptr, nullptr);
    // 2b. bias+mask table (A_bf dead; overlay)
    hipLaunchKernelGGL(bias_k, dim3(26, 25, 16), dim3(64), 0, stream, rpb, biasT2);
    // 3. flash MFMA windowed attention (8 waves/block) -> bf16
    hipLaunchKernelGGL(attn_mfma, dim3(NWIN * NHEADS), dim3(512), 0, stream,
                       Qb_bf, biasT2, O_bf);
    // 4. proj GEMM + unshift + residual -> f32 R, fused LN2 -> bf16 A_bf
    hipLaunchKernelGGL((gemm_mfma<2, 128>), dim3(1, TOK/64), dim3(512), 0, stream,
                       O_bf, projT, proj_b, R, 128, x, n2g, n2b, A_bf);
    // 5. fc1 + GELU -> bf16
    hipLaunchKernelGGL((gemm_mfma<3, 128>), dim3(4, TOK/64), dim3(512), 0, stream,
                       A_bf, fc1T, fc1_b, H_bf, 512, nullptr, nullptr, nullptr, nullptr);
    // 6. fc2 + residual -> f32 out
    hipLaunchKernelGGL((gemm_mfma<4, 512>), dim3(1, TOK/64), dim3(512), 0, stream,
                       H_bf, fc2T, fc2_b, out, 128, R, nullptr, nullptr, nullptr);
}